// Round 12
// baseline (416.887 us; speedup 1.0000x reference)
//
#include <hip/hip_runtime.h>
#include <math.h>

#define DA 64
#define NODEIN_DIM 224
#define EPSC 1e-8f

typedef short v8s __attribute__((ext_vector_type(8)));
typedef float v4f __attribute__((ext_vector_type(4)));
typedef unsigned short ushort_t;

__device__ __forceinline__ float siluf(float v) { return v / (1.0f + __expf(-v)); }

__device__ __forceinline__ void atomAddF(float* p, float v) {
#if defined(__HIP_DEVICE_COMPILE__)
  unsafeAtomicAdd(p, v);
#else
  atomicAdd(p, v);
#endif
}

__device__ __forceinline__ unsigned short f2bfu(float f) {
  union { float f; unsigned u; } v; v.f = f;
  unsigned r = v.u + 0x7fffu + ((v.u >> 16) & 1u);
  return (unsigned short)(r >> 16);
}
__device__ __forceinline__ short f2bfs(float f) { return (short)f2bfu(f); }
__device__ __forceinline__ float bf2f(ushort_t s) {
  union { unsigned u; float f; } v; v.u = ((unsigned)s) << 16; return v.f;
}

#define MU0 0.60653065971263342f
#define DMU ((1.0f - 0.60653065971263342f) / 19.0f)
#define BETA ((float)(1.0 / (0.039346934028736658 * 0.039346934028736658)))

// ---------------------------------------------------------------------------
__global__ __launch_bounds__(256) void cast_h(
    const float* __restrict__ hsrc, ushort_t* __restrict__ hb, int n4)
{
  const int i = blockIdx.x * blockDim.x + threadIdx.x;
  if (i < n4) {
    const float4 fv = ((const float4*)hsrc)[i];
    ushort4 o;
    o.x = f2bfu(fv.x); o.y = f2bfu(fv.y); o.z = f2bfu(fv.z); o.w = f2bfu(fv.w);
    ((ushort4*)hb)[i] = o;
  }
}

// ---------------------------------------------------------------------------
__global__ __launch_bounds__(256) void deg_count(
    const int* __restrict__ idx_i, int* __restrict__ deg, int E)
{
  const int stride = gridDim.x * blockDim.x;
  for (int e = blockIdx.x * blockDim.x + threadIdx.x; e < E; e += stride)
    atomicAdd(&deg[idx_i[e]], 1);
}

// ---------------------------------------------------------------------------
#define SCAN_B 64
#define SCAN_T (SCAN_B * 256)

__global__ __launch_bounds__(256) void deg_tsum(
    const int* __restrict__ deg, int* __restrict__ tsum, int N, int C)
{
  const int g = blockIdx.x * blockDim.x + threadIdx.x;
  const int lo = g * C;
  const int hi = (lo + C < N) ? (lo + C) : N;
  int s = 0;
  for (int i = lo; i < hi; ++i) s += deg[i];
  tsum[g] = s;
}

__global__ __launch_bounds__(256) void scan_tsum(int* __restrict__ tsum)
{
  __shared__ int ps[256];
  const int t = threadIdx.x;
  const int per = SCAN_T / 256;
  const int lo = t * per;
  int s = 0;
  for (int i = 0; i < per; ++i) s += tsum[lo + i];
  ps[t] = s;
  __syncthreads();
  if (t == 0) {
    int a = 0;
    for (int i = 0; i < 256; ++i) { const int v = ps[i]; ps[i] = a; a += v; }
  }
  __syncthreads();
  int acc = ps[t];
  for (int i = 0; i < per; ++i) {
    const int v = tsum[lo + i];
    tsum[lo + i] = acc;
    acc += v;
  }
}

__global__ __launch_bounds__(256) void write_csr(
    const int* __restrict__ deg, const int* __restrict__ tpre,
    int* __restrict__ rowstart, int* __restrict__ cursor,
    float* __restrict__ counts, int N, int C)
{
  const int g = blockIdx.x * blockDim.x + threadIdx.x;
  const int lo = g * C;
  const int hi = (lo + C < N) ? (lo + C) : N;
  int acc = tpre[g];
  for (int i = lo; i < hi; ++i) {
    const int d = deg[i];
    rowstart[i] = acc;
    cursor[i] = acc;
    counts[i] = (float)d;
    acc += d;
  }
  if (hi == N) rowstart[N] = acc;
}

// ---------------------------------------------------------------------------
__global__ __launch_bounds__(256) void bucket_edges(
    const int* __restrict__ idx_i, const int* __restrict__ idx_j,
    int* __restrict__ cursor, int* __restrict__ iperm,
    int* __restrict__ jperm, int E)
{
  const int stride = gridDim.x * blockDim.x;
  for (int e = blockIdx.x * blockDim.x + threadIdx.x; e < E; e += stride) {
    const int ii = idx_i[e];
    const int pos = atomicAdd(&cursor[ii], 1);
    iperm[pos] = ii;
    jperm[pos] = idx_j[e];
  }
}

// ---------------------------------------------------------------------------
// F12 (CSR order): gather + geometry + M1/RBF + M2 + transpose + M3 + att.
// W_out fragments in REGISTERS (16 VGPR) so LDS = 37.2 KB -> 4 blocks/CU
// (41 KB was 3 blocks/CU -> 23% occupancy; this kernel is latency-bound).
// ---------------------------------------------------------------------------
#define THS 72
__global__ __launch_bounds__(256) void edge_f12(
    const ushort_t* __restrict__ h_bf, const float* __restrict__ x,
    const int* __restrict__ iperm, const int* __restrict__ jperm,
    const float* __restrict__ W_in, const float* __restrict__ b_in,
    const float* __restrict__ W_h, const float* __restrict__ b_h,
    const float* __restrict__ W_out, const float* __restrict__ b_out,
    const float* __restrict__ W_att, const float* __restrict__ b_att,
    float* __restrict__ dirb, ushort_t* __restrict__ heb,
    float* __restrict__ expl, float* __restrict__ denom, int E)
{
  __shared__ ushort_t sB1[8 * 512];    // 8 KB: W_in fragments (kc*2+nt)
  __shared__ ushort_t sB2[20 * 512];   // 20 KB: W_h fragments (kc*4+nt)
  __shared__ ushort_t tH[4][16 * THS]; // 9 KB: per-wave transpose tile

  const int tid = threadIdx.x;
  for (int idx = tid; idx < 8 * 512; idx += 256) {
    const int j = idx & 7;
    const int ln = (idx >> 3) & 63;
    const int f = idx >> 9;               // kc*2+nt
    const int k = (f >> 1) * 32 + (ln >> 4) * 8 + j;
    const int col = (f & 1) * 16 + (ln & 15);
    sB1[idx] = (col < 20) ? f2bfu(W_in[k * 20 + col]) : (ushort_t)0;
  }
  for (int idx = tid; idx < 20 * 512; idx += 256) {
    const int j = idx & 7;
    const int ln = (idx >> 3) & 63;
    const int f = idx >> 9;               // kc*4+nt
    const int k = (f >> 2) * 32 + (ln >> 4) * 8 + j;
    const int col = (f & 3) * 16 + (ln & 15);
    sB2[idx] = (k < 149) ? f2bfu(W_h[k * 64 + col]) : (ushort_t)0;
  }
  __syncthreads();

  const int gtid = blockIdx.x * blockDim.x + tid;
  const int wid = gtid >> 6;
  const int lane = tid & 63;
  const int w = tid >> 6;
  const int nw = (gridDim.x * blockDim.x) >> 6;
  const int l15 = lane & 15;
  const int q = lane >> 4;

  const ushort_t* b1l = sB1 + lane * 8;
  const ushort_t* b2l = sB2 + lane * 8;

  // W_out fragments in registers (round-6 layout)
  v8s bfr3[2][2];
  #pragma unroll
  for (int kc = 0; kc < 2; ++kc)
    #pragma unroll
    for (int nt = 0; nt < 2; ++nt)
      #pragma unroll
      for (int j = 0; j < 8; ++j) {
        const int k = kc * 32 + q * 8 + j;
        const int col = nt * 16 + l15;
        bfr3[kc][nt][j] = f2bfs(W_out[k * 32 + col]);
      }

  float bin[2], mu[2];
  #pragma unroll
  for (int nt = 0; nt < 2; ++nt) {
    const int col = nt * 16 + l15;
    bin[nt] = (col < 20) ? b_in[col] : 0.0f;
    mu[nt] = MU0 + (float)col * DMU;
  }
  float bias2[4];
  #pragma unroll
  for (int nt = 0; nt < 4; ++nt) bias2[nt] = b_h[nt * 16 + l15];
  float bias3[2];
  #pragma unroll
  for (int nt = 0; nt < 2; ++nt) bias3[nt] = b_out[nt * 16 + l15];

  v8s battf;
  #pragma unroll
  for (int j = 0; j < 8; ++j)
    battf[j] = (l15 < 4) ? f2bfs(W_att[(q * 8 + j) * 4 + l15]) : (short)0;
  const float bav = (l15 < 4) ? b_att[l15] : 0.0f;

  const int ntiles = (E + 15) >> 4;

  int iiC = 0, jjC = 0;
  v8s afr[4];
  if (wid < ntiles) {
    const int row0 = wid * 16 + l15;
    const int rowL0 = (row0 < E) ? row0 : (E - 1);
    iiC = iperm[rowL0];
    jjC = jperm[rowL0];
    afr[0] = *(const v8s*)(h_bf + (size_t)iiC * 64 + q * 8);
    afr[1] = *(const v8s*)(h_bf + (size_t)iiC * 64 + 32 + q * 8);
    afr[2] = *(const v8s*)(h_bf + (size_t)jjC * 64 + q * 8);
    afr[3] = *(const v8s*)(h_bf + (size_t)jjC * 64 + 32 + q * 8);
  }

  for (int t = wid; t < ntiles; t += nw) {
    const int tn = t + nw;
    int iiN = 0, jjN = 0;
    v8s nfr[4];
    if (tn < ntiles) {
      const int rowN = tn * 16 + l15;
      const int rowLN = (rowN < E) ? rowN : (E - 1);
      iiN = iperm[rowLN];
      jjN = jperm[rowLN];
      nfr[0] = *(const v8s*)(h_bf + (size_t)iiN * 64 + q * 8);
      nfr[1] = *(const v8s*)(h_bf + (size_t)iiN * 64 + 32 + q * 8);
      nfr[2] = *(const v8s*)(h_bf + (size_t)jjN * 64 + q * 8);
      nfr[3] = *(const v8s*)(h_bf + (size_t)jjN * 64 + 32 + q * 8);
    }

    const int row = t * 16 + l15;
    float dval = 0.0f;
    if (lane < 16 && row < E) {
      const float rx = x[jjC * 3 + 0] - x[iiC * 3 + 0];
      const float ry = x[jjC * 3 + 1] - x[iiC * 3 + 1];
      const float rz = x[jjC * 3 + 2] - x[iiC * 3 + 2];
      const float d = sqrtf(rx * rx + ry * ry + rz * rz + EPSC);
      dval = d;
      const float inv = 1.0f / (d + EPSC);
      dirb[row * 3 + 0] = rx * inv;
      dirb[row * 3 + 1] = ry * inv;
      dirb[row * 3 + 2] = rz * inv;
    }

    // M1: [16,128] x W_in
    v4f acc1[2];
    #pragma unroll
    for (int nt = 0; nt < 2; ++nt) {
      v4f a = {0.f, 0.f, 0.f, 0.f};
      #pragma unroll
      for (int kc = 0; kc < 4; ++kc) {
        const v8s bfrag = *(const v8s*)(b1l + (kc * 2 + nt) * 512);
        a = __builtin_amdgcn_mfma_f32_16x16x32_bf16(afr[kc], bfrag, a, 0, 0, 0);
      }
      acc1[nt] = a;
    }

    float dr[4], edr[4];
    #pragma unroll
    for (int r = 0; r < 4; ++r) {
      dr[r] = __shfl(dval, q * 4 + r);
      edr[r] = __expf(-dr[r]);
    }
    #pragma unroll
    for (int nt = 0; nt < 2; ++nt) {
      const int col = nt * 16 + l15;
      #pragma unroll
      for (int r = 0; r < 4; ++r) {
        ushort_t ov;
        if (col < 20) {
          const float tt = edr[r] - mu[nt];
          ov = f2bfu((acc1[nt][r] + bin[nt]) * __expf(-BETA * tt * tt));
        } else if (col == 20) {
          ov = f2bfu(dr[r]);
        } else {
          ov = 0;
        }
        tH[w][(q * 4 + r) * THS + col] = ov;
      }
    }
    __builtin_amdgcn_wave_barrier();

    const v8s afr4 = *(const v8s*)&tH[w][l15 * THS + q * 8];
    __builtin_amdgcn_wave_barrier();

    // M2: [16,160] x W_h
    v4f acc2[4];
    #pragma unroll
    for (int nt = 0; nt < 4; ++nt) {
      v4f a = {0.f, 0.f, 0.f, 0.f};
      #pragma unroll
      for (int kc = 0; kc < 4; ++kc) {
        const v8s bfrag = *(const v8s*)(b2l + (kc * 4 + nt) * 512);
        a = __builtin_amdgcn_mfma_f32_16x16x32_bf16(afr[kc], bfrag, a, 0, 0, 0);
      }
      const v8s bfrag4 = *(const v8s*)(b2l + (4 * 4 + nt) * 512);
      a = __builtin_amdgcn_mfma_f32_16x16x32_bf16(afr4, bfrag4, a, 0, 0, 0);
      acc2[nt] = a;
    }

    #pragma unroll
    for (int nt = 0; nt < 4; ++nt) {
      #pragma unroll
      for (int r = 0; r < 4; ++r)
        tH[w][(q * 4 + r) * THS + nt * 16 + l15] =
            f2bfu(siluf(acc2[nt][r] + bias2[nt]));
    }
    __builtin_amdgcn_wave_barrier();

    v8s af3[2];
    af3[0] = *(const v8s*)&tH[w][l15 * THS + q * 8];
    af3[1] = *(const v8s*)&tH[w][l15 * THS + 32 + q * 8];

    v4f acc3[2];
    #pragma unroll
    for (int nt = 0; nt < 2; ++nt) {
      v4f a = {0.f, 0.f, 0.f, 0.f};
      #pragma unroll
      for (int kc = 0; kc < 2; ++kc)
        a = __builtin_amdgcn_mfma_f32_16x16x32_bf16(af3[kc], bfr3[kc][nt], a, 0, 0, 0);
      acc3[nt] = a;
    }
    __builtin_amdgcn_wave_barrier();

    const int rowb = t * 16 + q * 4;
    #pragma unroll
    for (int nt = 0; nt < 2; ++nt) {
      const int col = nt * 16 + l15;
      #pragma unroll
      for (int r = 0; r < 4; ++r) {
        const ushort_t hv = f2bfu(acc3[nt][r] + bias3[nt]);
        tH[w][(q * 4 + r) * THS + col] = hv;
        if (rowb + r < E) heb[(size_t)(rowb + r) * 32 + col] = hv;
      }
    }
    __builtin_amdgcn_wave_barrier();

    const v8s afA = *(const v8s*)&tH[w][l15 * THS + q * 8];
    v4f az = {0.f, 0.f, 0.f, 0.f};
    const v4f aacc = __builtin_amdgcn_mfma_f32_16x16x32_bf16(afA, battf, az, 0, 0, 0);

    int ii_r[4];
    #pragma unroll
    for (int r = 0; r < 4; ++r) ii_r[r] = __shfl(iiC, q * 4 + r);

    if (l15 < 4) {
      #pragma unroll
      for (int r = 0; r < 4; ++r) {
        if (rowb + r < E) {
          const float la = aacc[r] + bav;
          const float l = (la > 0.f) ? la : 2.0f * (__expf(0.5f * la) - 1.0f);
          const float ev = __expf(l);
          expl[(size_t)(rowb + r) * 4 + l15] = ev;
          atomAddF(&denom[ii_r[r] * 4 + l15], ev);
        }
      }
    }
    __builtin_amdgcn_wave_barrier();

    iiC = iiN; jjC = jjN;
    afr[0] = nfr[0]; afr[1] = nfr[1]; afr[2] = nfr[2]; afr[3] = nfr[3];
  }
}

// ---------------------------------------------------------------------------
// mix_kernel (CSR order)
// ---------------------------------------------------------------------------
__global__ __launch_bounds__(256) void mix_kernel(
    const ushort_t* __restrict__ heb, const int* __restrict__ iperm,
    const float* __restrict__ expl, const float* __restrict__ denom,
    const float* __restrict__ W_xmix, const float* __restrict__ w_vmix,
    ushort_t* __restrict__ mixE, float* __restrict__ pE, int E)
{
  const int tid = blockIdx.x * blockDim.x + threadIdx.x;
  const int wid = tid >> 6;
  const int lane = threadIdx.x & 63;
  const int nw = (gridDim.x * blockDim.x) >> 6;
  const int l15 = lane & 15;
  const int q = lane >> 4;

  v8s bfr[4][2];
  #pragma unroll
  for (int kc = 0; kc < 4; ++kc)
    #pragma unroll
    for (int nt = 0; nt < 2; ++nt)
      #pragma unroll
      for (int j = 0; j < 8; ++j) {
        const int k = kc * 32 + q * 8 + j;
        const int col = nt * 16 + l15;
        bfr[kc][nt][j] = f2bfs(W_xmix[k * 32 + col]);
      }
  float wv[2];
  wv[0] = w_vmix[l15];
  wv[1] = w_vmix[16 + l15];

  const int ntiles = (E + 15) >> 4;
  for (int t = wid; t < ntiles; t += nw) {
    const int row = t * 16 + l15;
    const int rowL = (row < E) ? row : (E - 1);
    const int ii = iperm[rowL];
    float att[4];
    #pragma unroll
    for (int hh = 0; hh < 4; ++hh)
      att[hh] = expl[(size_t)rowL * 4 + hh] / (denom[ii * 4 + hh] + EPSC);

    const v8s hech = *(const v8s*)(heb + (size_t)rowL * 32 + q * 8);
    float hef[8];
    #pragma unroll
    for (int j = 0; j < 8; ++j) hef[j] = bf2f((ushort_t)hech[j]);

    v8s afr[4];
    #pragma unroll
    for (int kc = 0; kc < 4; ++kc)
      #pragma unroll
      for (int j = 0; j < 8; ++j)
        afr[kc][j] = f2bfs(att[kc] * hef[j]);

    v4f acc[2];
    #pragma unroll
    for (int nt = 0; nt < 2; ++nt) {
      v4f a = {0.f, 0.f, 0.f, 0.f};
      #pragma unroll
      for (int kc = 0; kc < 4; ++kc)
        a = __builtin_amdgcn_mfma_f32_16x16x32_bf16(afr[kc], bfr[kc][nt], a, 0, 0, 0);
      acc[nt] = a;
    }

    const int rowb = t * 16 + q * 4;
    float pr[4];
    #pragma unroll
    for (int r = 0; r < 4; ++r) {
      const float m0 = tanhf(acc[0][r]);
      const float m1 = tanhf(acc[1][r]);
      if (rowb + r < E) {
        mixE[(size_t)(rowb + r) * 32 + l15] = f2bfu(m0);
        mixE[(size_t)(rowb + r) * 32 + 16 + l15] = f2bfu(m1);
      }
      pr[r] = m0 * wv[0] + m1 * wv[1];
    }
    #pragma unroll
    for (int r = 0; r < 4; ++r) {
      pr[r] += __shfl_xor(pr[r], 1);
      pr[r] += __shfl_xor(pr[r], 2);
      pr[r] += __shfl_xor(pr[r], 4);
      pr[r] += __shfl_xor(pr[r], 8);
      if (l15 == 0 && rowb + r < E) pE[rowb + r] = pr[r];
    }
  }
}

// ---------------------------------------------------------------------------
// node_reduce: wave per node, streaming CSR reads, 4x unrolled
// ---------------------------------------------------------------------------
__global__ __launch_bounds__(256) void node_reduce(
    const int* __restrict__ rowstart,
    const ushort_t* __restrict__ heb, const ushort_t* __restrict__ mixE,
    const float* __restrict__ expl, const float* __restrict__ denom,
    const float* __restrict__ dirb, const float* __restrict__ pE,
    ushort_t* __restrict__ hsem, float* __restrict__ comb_sum,
    float* __restrict__ dv_sum, int N)
{
  const int tid = blockIdx.x * blockDim.x + threadIdx.x;
  const int wid = tid >> 6;
  const int lane = threadIdx.x & 63;
  const int nw = (gridDim.x * blockDim.x) >> 6;
  const int hh = lane >> 5;
  const int eb = lane & 31;

  for (int n = wid; n < N; n += nw) {
    const int s = rowstart[n];
    const int epd = rowstart[n + 1];
    float semA = 0.f, semB = 0.f;
    float cx = 0.f, cy = 0.f, cz = 0.f;
    float dvx = 0.f, dvy = 0.f, dvz = 0.f;
    int k = s;
    const int e4 = s + ((epd - s) & ~3);
    for (; k < e4; k += 4) {
      float he[4], ea[4], ec[4], dx[4], dy[4], dz[4], m[4], pe[4];
      #pragma unroll
      for (int u = 0; u < 4; ++u) {
        he[u] = bf2f(heb[(size_t)(k + u) * 32 + eb]);
        ea[u] = expl[(size_t)(k + u) * 4 + hh];
        ec[u] = expl[(size_t)(k + u) * 4 + 2 + hh];
        dx[u] = dirb[(k + u) * 3 + 0];
        dy[u] = dirb[(k + u) * 3 + 1];
        dz[u] = dirb[(k + u) * 3 + 2];
      }
      if (lane < 32) {
        #pragma unroll
        for (int u = 0; u < 4; ++u)
          m[u] = bf2f(mixE[(size_t)(k + u) * 32 + lane]);
      }
      if (lane == 0) {
        #pragma unroll
        for (int u = 0; u < 4; ++u) pe[u] = pE[k + u];
      }
      #pragma unroll
      for (int u = 0; u < 4; ++u) {
        semA += ea[u] * he[u];
        semB += ec[u] * he[u];
        if (lane < 32) {
          cx += dx[u] * m[u]; cy += dy[u] * m[u]; cz += dz[u] * m[u];
        }
        if (lane == 0) {
          dvx += dx[u] * pe[u]; dvy += dy[u] * pe[u]; dvz += dz[u] * pe[u];
        }
      }
    }
    for (; k < epd; ++k) {
      const float he = bf2f(heb[(size_t)k * 32 + eb]);
      const float ea = expl[(size_t)k * 4 + hh];
      const float ec = expl[(size_t)k * 4 + 2 + hh];
      semA += ea * he;
      semB += ec * he;
      const float dx = dirb[k * 3 + 0];
      const float dy = dirb[k * 3 + 1];
      const float dz = dirb[k * 3 + 2];
      if (lane < 32) {
        const float m = bf2f(mixE[(size_t)k * 32 + lane]);
        cx += dx * m; cy += dy * m; cz += dz * m;
      }
      if (lane == 0) {
        const float pe = pE[k];
        dvx += dx * pe; dvy += dy * pe; dvz += dz * pe;
      }
    }
    const float dA = denom[n * 4 + hh] + EPSC;
    const float dB = denom[n * 4 + 2 + hh] + EPSC;
    hsem[(size_t)n * 128 + lane] = f2bfu(semA / dA);
    hsem[(size_t)n * 128 + 64 + lane] = f2bfu(semB / dB);
    if (lane < 32) {
      comb_sum[(size_t)n * 96 + lane * 3 + 0] = cx;
      comb_sum[(size_t)n * 96 + lane * 3 + 1] = cy;
      comb_sum[(size_t)n * 96 + lane * 3 + 2] = cz;
    }
    if (lane == 0) {
      dv_sum[n * 3 + 0] = dvx;
      dv_sum[n * 3 + 1] = dvy;
      dv_sum[n * 3 + 2] = dvz;
    }
  }
}

// ---------------------------------------------------------------------------
// C1 (MFMA): spatial MLP (post1/post2) + node1 -> nh bf16 [N,128]
// ---------------------------------------------------------------------------
#define W1S 232
__global__ __launch_bounds__(256) void node_c1_mfma(
    const ushort_t* __restrict__ h_bf, const ushort_t* __restrict__ hsem,
    const float* __restrict__ comb_sum, const float* __restrict__ counts,
    const float* __restrict__ W_post1, const float* __restrict__ b_post1,
    const float* __restrict__ W_post2, const float* __restrict__ b_post2,
    const float* __restrict__ W_node1, const float* __restrict__ b_node1,
    ushort_t* __restrict__ nh_out, int N)
{
  __shared__ ushort_t sW1t[128 * W1S];
  __shared__ ushort_t tp[4][16 * THS];

  const int tid = threadIdx.x;
  for (int idx = tid; idx < 224 * 128; idx += 256) {
    const int k = idx >> 7;
    const int c = idx & 127;
    sW1t[c * W1S + k] = f2bfu(W_node1[idx]);
  }
  __syncthreads();

  const int lane = tid & 63;
  const int w = tid >> 6;
  const int l15 = lane & 15;
  const int q = lane >> 4;

  v8s bp1[4];
  #pragma unroll
  for (int nt = 0; nt < 4; ++nt)
    #pragma unroll
    for (int j = 0; j < 8; ++j)
      bp1[nt][j] = f2bfs(W_post1[(q * 8 + j) * 64 + nt * 16 + l15]);
  v8s bp2[2][2];
  #pragma unroll
  for (int kc = 0; kc < 2; ++kc)
    #pragma unroll
    for (int nt = 0; nt < 2; ++nt)
      #pragma unroll
      for (int j = 0; j < 8; ++j)
        bp2[kc][nt][j] = f2bfs(W_post2[(kc * 32 + q * 8 + j) * 32 + nt * 16 + l15]);
  float bb1[4];
  #pragma unroll
  for (int nt = 0; nt < 4; ++nt) bb1[nt] = b_post1[nt * 16 + l15];
  float bb2[2];
  #pragma unroll
  for (int nt = 0; nt < 2; ++nt) bb2[nt] = b_post2[nt * 16 + l15];
  float b1[8];
  #pragma unroll
  for (int nt = 0; nt < 8; ++nt) b1[nt] = b_node1[nt * 16 + l15];

  const int gw = blockIdx.x * 4 + w;
  const int nwv = gridDim.x * 4;
  const int ntiles = (N + 15) >> 4;

  for (int t = gw; t < ntiles; t += nwv) {
    const int row = t * 16 + l15;
    const int rowL = (row < N) ? row : (N - 1);

    const float inv = 1.0f / fmaxf(counts[rowL], 1.0f);
    const float4* cs = (const float4*)(comb_sum + (size_t)rowL * 96 + q * 24);
    float cf[24];
    #pragma unroll
    for (int b = 0; b < 6; ++b) {
      const float4 cv = cs[b];
      cf[b * 4 + 0] = cv.x; cf[b * 4 + 1] = cv.y;
      cf[b * 4 + 2] = cv.z; cf[b * 4 + 3] = cv.w;
    }
    v8s a1;
    #pragma unroll
    for (int j = 0; j < 8; ++j) {
      const float vx = cf[j * 3 + 0] * inv;
      const float vy = cf[j * 3 + 1] * inv;
      const float vz = cf[j * 3 + 2] * inv;
      a1[j] = f2bfs(vx * vx + vy * vy + vz * vz);
    }

    v4f p1[4];
    #pragma unroll
    for (int nt = 0; nt < 4; ++nt) {
      v4f a = {0.f, 0.f, 0.f, 0.f};
      p1[nt] = __builtin_amdgcn_mfma_f32_16x16x32_bf16(a1, bp1[nt], a, 0, 0, 0);
    }
    #pragma unroll
    for (int nt = 0; nt < 4; ++nt)
      #pragma unroll
      for (int r = 0; r < 4; ++r)
        tp[w][(q * 4 + r) * THS + nt * 16 + l15] =
            f2bfu(siluf(p1[nt][r] + bb1[nt]));
    __builtin_amdgcn_wave_barrier();

    v8s a2[2];
    a2[0] = *(const v8s*)&tp[w][l15 * THS + q * 8];
    a2[1] = *(const v8s*)&tp[w][l15 * THS + 32 + q * 8];

    v4f p2[2];
    #pragma unroll
    for (int nt = 0; nt < 2; ++nt) {
      v4f a = {0.f, 0.f, 0.f, 0.f};
      #pragma unroll
      for (int kc = 0; kc < 2; ++kc)
        a = __builtin_amdgcn_mfma_f32_16x16x32_bf16(a2[kc], bp2[kc][nt], a, 0, 0, 0);
      p2[nt] = a;
    }
    __builtin_amdgcn_wave_barrier();
    #pragma unroll
    for (int nt = 0; nt < 2; ++nt)
      #pragma unroll
      for (int r = 0; r < 4; ++r)
        tp[w][(q * 4 + r) * THS + nt * 16 + l15] =
            f2bfu(siluf(p2[nt][r] + bb2[nt]));
    __builtin_amdgcn_wave_barrier();

    v8s af[7];
    af[0] = *(const v8s*)(h_bf + (size_t)rowL * 64 + q * 8);
    af[1] = *(const v8s*)(h_bf + (size_t)rowL * 64 + 32 + q * 8);
    #pragma unroll
    for (int kc = 0; kc < 4; ++kc)
      af[2 + kc] = *(const v8s*)(hsem + (size_t)rowL * 128 + kc * 32 + q * 8);
    af[6] = *(const v8s*)&tp[w][l15 * THS + q * 8];

    v4f acc[8];
    #pragma unroll
    for (int nt = 0; nt < 8; ++nt) acc[nt] = (v4f){0.f, 0.f, 0.f, 0.f};
    #pragma unroll
    for (int kc = 0; kc < 7; ++kc) {
      #pragma unroll
      for (int nt = 0; nt < 8; ++nt) {
        const v8s bfrag =
            *(const v8s*)&sW1t[(nt * 16 + l15) * W1S + kc * 32 + q * 8];
        acc[nt] = __builtin_amdgcn_mfma_f32_16x16x32_bf16(af[kc], bfrag, acc[nt], 0, 0, 0);
      }
    }

    const int rowb = t * 16 + q * 4;
    #pragma unroll
    for (int nt = 0; nt < 8; ++nt) {
      #pragma unroll
      for (int r = 0; r < 4; ++r)
        if (rowb + r < N)
          nh_out[(size_t)(rowb + r) * 128 + nt * 16 + l15] =
              f2bfu(siluf(acc[nt][r] + b1[nt]));
    }
  }
}

// ---------------------------------------------------------------------------
// C2 (MFMA): node2 + vel1 + gate + v/x update
// ---------------------------------------------------------------------------
__global__ __launch_bounds__(256) void node_c2_mfma(
    const float* __restrict__ h, const float* __restrict__ x,
    const float* __restrict__ v, const ushort_t* __restrict__ nh,
    const float* __restrict__ dv_sum, const float* __restrict__ counts,
    const float* __restrict__ W_node2, const float* __restrict__ b_node2,
    const float* __restrict__ W_vel1, const float* __restrict__ b_vel1,
    const float* __restrict__ W_vel2,
    float* __restrict__ out, int N)
{
  __shared__ ushort_t sW2[16 * 64 * 8];
  __shared__ ushort_t sWv[4 * 64 * 8];
  __shared__ ushort_t tH[4][16 * THS];
  __shared__ float sg[4][16];

  const int tid = threadIdx.x;
  for (int idx = tid; idx < 16 * 64 * 8; idx += 256) {
    const int j = idx & 7;
    const int ln = (idx >> 3) & 63;
    const int f = idx >> 9;
    const int k = (f >> 2) * 32 + (ln >> 4) * 8 + j;
    const int col = (f & 3) * 16 + (ln & 15);
    sW2[idx] = f2bfu(W_node2[k * 64 + col]);
  }
  for (int idx = tid; idx < 4 * 64 * 8; idx += 256) {
    const int j = idx & 7;
    const int ln = (idx >> 3) & 63;
    const int f = idx >> 9;
    const int k = (f >> 1) * 32 + (ln >> 4) * 8 + j;
    const int col = (f & 1) * 16 + (ln & 15);
    sWv[idx] = f2bfu(W_vel1[k * 32 + col]);
  }
  __syncthreads();

  const int lane = tid & 63;
  const int w = tid >> 6;
  const int l15 = lane & 15;
  const int q = lane >> 4;

  const ushort_t* w2l = sW2 + lane * 8;
  const ushort_t* wvl = sWv + lane * 8;

  float b2[4];
  #pragma unroll
  for (int nt = 0; nt < 4; ++nt) b2[nt] = b_node2[nt * 16 + l15];
  float bv[2];
  #pragma unroll
  for (int nt = 0; nt < 2; ++nt) bv[nt] = b_vel1[nt * 16 + l15];
  float wv2[2];
  #pragma unroll
  for (int nt = 0; nt < 2; ++nt) wv2[nt] = W_vel2[nt * 16 + l15];

  const int gw = blockIdx.x * 4 + w;
  const int nwv = gridDim.x * 4;
  const int ntiles = (N + 15) >> 4;

  for (int t = gw; t < ntiles; t += nwv) {
    const int row = t * 16 + l15;
    const int rowL = (row < N) ? row : (N - 1);

    v8s af[4];
    #pragma unroll
    for (int kc = 0; kc < 4; ++kc)
      af[kc] = *(const v8s*)(nh + (size_t)rowL * 128 + kc * 32 + q * 8);

    v4f acc[4];
    #pragma unroll
    for (int nt = 0; nt < 4; ++nt) {
      v4f a = {0.f, 0.f, 0.f, 0.f};
      #pragma unroll
      for (int kc = 0; kc < 4; ++kc) {
        const v8s bfrag = *(const v8s*)(w2l + (kc * 4 + nt) * 512);
        a = __builtin_amdgcn_mfma_f32_16x16x32_bf16(af[kc], bfrag, a, 0, 0, 0);
      }
      acc[nt] = a;
    }

    const int rowb = t * 16 + q * 4;
    #pragma unroll
    for (int nt = 0; nt < 4; ++nt) {
      const int col = nt * 16 + l15;
      #pragma unroll
      for (int r = 0; r < 4; ++r) {
        const int n = rowb + r;
        if (n < N) {
          const float hu = h[(size_t)n * 64 + col] + siluf(acc[nt][r] + b2[nt]);
          out[(size_t)n * 64 + col] = hu;
          tH[w][(q * 4 + r) * THS + col] = f2bfu(hu);
        }
      }
    }
    __builtin_amdgcn_wave_barrier();

    v8s a2[2];
    a2[0] = *(const v8s*)&tH[w][l15 * THS + q * 8];
    a2[1] = *(const v8s*)&tH[w][l15 * THS + 32 + q * 8];
    v4f av[2];
    #pragma unroll
    for (int nt = 0; nt < 2; ++nt) {
      v4f a = {0.f, 0.f, 0.f, 0.f};
      #pragma unroll
      for (int kc = 0; kc < 2; ++kc) {
        const v8s bfrag = *(const v8s*)(wvl + (kc * 2 + nt) * 512);
        a = __builtin_amdgcn_mfma_f32_16x16x32_bf16(a2[kc], bfrag, a, 0, 0, 0);
      }
      av[nt] = a;
    }

    #pragma unroll
    for (int r = 0; r < 4; ++r) {
      float pr = siluf(av[0][r] + bv[0]) * wv2[0] +
                 siluf(av[1][r] + bv[1]) * wv2[1];
      pr += __shfl_xor(pr, 1);
      pr += __shfl_xor(pr, 2);
      pr += __shfl_xor(pr, 4);
      pr += __shfl_xor(pr, 8);
      if (l15 == 0) sg[w][q * 4 + r] = 2.0f / (1.0f + __expf(-pr));
    }
    __builtin_amdgcn_wave_barrier();

    if (lane < 48) {
      const int rr = lane / 3;
      const int c = lane % 3;
      const int n = t * 16 + rr;
      if (n < N) {
        const float gate = sg[w][rr];
        const float cnt = fmaxf(counts[n], 1.0f);
        const float dv = dv_sum[n * 3 + c] / cnt;
        const float vu = gate * v[n * 3 + c] + dv;
        out[(size_t)N * 64 + (size_t)n * 3 + c] = x[n * 3 + c] + vu;
        out[(size_t)N * 64 + (size_t)N * 3 + (size_t)n * 3 + c] = vu;
      }
    }
    __builtin_amdgcn_wave_barrier();
  }
}

// ---------------------------------------------------------------------------
extern "C" void kernel_launch(void* const* d_in, const int* in_sizes, int n_in,
                              void* d_out, int out_size, void* d_ws, size_t ws_size,
                              hipStream_t stream) {
  const float* h   = (const float*)d_in[0];
  const float* x   = (const float*)d_in[1];
  const float* v   = (const float*)d_in[2];
  const int* idx_i = (const int*)d_in[3];
  const int* idx_j = (const int*)d_in[4];
  const float* W_edge_in  = (const float*)d_in[5];
  const float* b_edge_in  = (const float*)d_in[6];
  const float* W_edge_h   = (const float*)d_in[7];
  const float* b_edge_h   = (const float*)d_in[8];
  const float* W_edge_out = (const float*)d_in[9];
  const float* b_edge_out = (const float*)d_in[10];
  const float* W_att      = (const float*)d_in[11];
  const float* b_att      = (const float*)d_in[12];
  const float* W_x_mix    = (const float*)d_in[13];
  const float* W_node1    = (const float*)d_in[14];
  const float* b_node1    = (const float*)d_in[15];
  const float* W_node2    = (const float*)d_in[16];
  const float* b_node2    = (const float*)d_in[17];
  const float* W_post1    = (const float*)d_in[18];
  const float* b_post1    = (const float*)d_in[19];
  const float* W_post2    = (const float*)d_in[20];
  const float* b_post2    = (const float*)d_in[21];
  const float* W_vel1     = (const float*)d_in[22];
  const float* b_vel1     = (const float*)d_in[23];
  const float* W_vel2     = (const float*)d_in[24];
  const float* w_v_mix    = (const float*)d_in[25];

  const int E = in_sizes[3];
  const int N = in_sizes[0] / DA;

  float* ws = (float*)d_ws;
  size_t off = 0;
  float* denom    = ws + off; off += (size_t)N * 4;     // zeroed
  int*   deg      = (int*)(ws + off); off += (size_t)N; // zeroed
  const size_t zeroBytes = off * sizeof(float);
  float* counts   = ws + off; off += (size_t)N;
  int*   rowstart = (int*)(ws + off); off += (size_t)N + 4;
  int*   cursor   = (int*)(ws + off); off += (size_t)N;
  int*   tsum     = (int*)(ws + off); off += (size_t)SCAN_T;
  int*   iperm    = (int*)(ws + off); off += (size_t)E;
  int*   jperm    = (int*)(ws + off); off += (size_t)E;
  float* pE       = ws + off; off += (size_t)E;
  float* expl     = ws + off; off += (size_t)E * 4;
  float* dirb     = ws + off; off += (size_t)E * 3;
  float* hsemR    = ws + off; off += (size_t)N * 64;    // hsem bf16 [N,128]
  float* comb_sum = ws + off; off += (size_t)N * 96;
  float* dv_sum   = ws + off; off += (size_t)N * 4;
  float* hbfR     = ws + off; off += (size_t)N * 32;    // h_bf bf16 [N,64]
  float* fltR     = ws + off; off += (size_t)E * 16;    // mixE / nh
  float* hebR     = ws + off; off += (size_t)E * 16;    // heb bf16 [E,32]

  ushort_t* h_bf = (ushort_t*)hbfR;
  ushort_t* hsem = (ushort_t*)hsemR;
  ushort_t* heb  = (ushort_t*)hebR;
  ushort_t* mixE = (ushort_t*)fltR;
  ushort_t* nh   = (ushort_t*)fltR;  // aliases mixE (dead after node_reduce)

  hipMemsetAsync(d_ws, 0, zeroBytes, stream);

  {
    const int n4 = (N * 64) / 4;
    cast_h<<<(n4 + 255) / 256, 256, 0, stream>>>(h, h_bf, n4);
  }
  deg_count<<<512, 256, 0, stream>>>(idx_i, deg, E);
  {
    const int C = (N + SCAN_T - 1) / SCAN_T;
    deg_tsum<<<SCAN_B, 256, 0, stream>>>(deg, tsum, N, C);
    scan_tsum<<<1, 256, 0, stream>>>(tsum);
    write_csr<<<SCAN_B, 256, 0, stream>>>(deg, tsum, rowstart, cursor, counts, N, C);
  }
  bucket_edges<<<512, 256, 0, stream>>>(idx_i, idx_j, cursor, iperm, jperm, E);
  edge_f12<<<1024, 256, 0, stream>>>(h_bf, x, iperm, jperm,
                                     W_edge_in, b_edge_in, W_edge_h, b_edge_h,
                                     W_edge_out, b_edge_out, W_att, b_att,
                                     dirb, heb, expl, denom, E);
  mix_kernel<<<1024, 256, 0, stream>>>(heb, iperm, expl, denom, W_x_mix,
                                       w_v_mix, mixE, pE, E);
  node_reduce<<<2048, 256, 0, stream>>>(rowstart, heb, mixE, expl, denom,
                                        dirb, pE, hsem, comb_sum, dv_sum, N);
  node_c1_mfma<<<512, 256, 0, stream>>>(
      h_bf, hsem, comb_sum, counts, W_post1, b_post1, W_post2, b_post2,
      W_node1, b_node1, nh, N);
  node_c2_mfma<<<512, 256, 0, stream>>>(
      h, x, v, nh, dv_sum, counts, W_node2, b_node2, W_vel1, b_vel1, W_vel2,
      (float*)d_out, N);
}

// Round 13
// 404.603 us; speedup vs baseline: 1.0304x; 1.0304x over previous
//
#include <hip/hip_runtime.h>
#include <math.h>

#define DA 64
#define NODEIN_DIM 224
#define EPSC 1e-8f

typedef short v8s __attribute__((ext_vector_type(8)));
typedef float v4f __attribute__((ext_vector_type(4)));
typedef unsigned short ushort_t;

__device__ __forceinline__ float siluf(float v) { return v / (1.0f + __expf(-v)); }

__device__ __forceinline__ void atomAddF(float* p, float v) {
#if defined(__HIP_DEVICE_COMPILE__)
  unsafeAtomicAdd(p, v);
#else
  atomicAdd(p, v);
#endif
}

__device__ __forceinline__ unsigned short f2bfu(float f) {
  union { float f; unsigned u; } v; v.f = f;
  unsigned r = v.u + 0x7fffu + ((v.u >> 16) & 1u);
  return (unsigned short)(r >> 16);
}
__device__ __forceinline__ short f2bfs(float f) { return (short)f2bfu(f); }
__device__ __forceinline__ float bf2f(ushort_t s) {
  union { unsigned u; float f; } v; v.u = ((unsigned)s) << 16; return v.f;
}

#define MU0 0.60653065971263342f
#define DMU ((1.0f - 0.60653065971263342f) / 19.0f)
#define BETA ((float)(1.0 / (0.039346934028736658 * 0.039346934028736658)))

// ---------------------------------------------------------------------------
__global__ __launch_bounds__(256) void cast_h(
    const float* __restrict__ hsrc, ushort_t* __restrict__ hb, int n4)
{
  const int i = blockIdx.x * blockDim.x + threadIdx.x;
  if (i < n4) {
    const float4 fv = ((const float4*)hsrc)[i];
    ushort4 o;
    o.x = f2bfu(fv.x); o.y = f2bfu(fv.y); o.z = f2bfu(fv.z); o.w = f2bfu(fv.w);
    ((ushort4*)hb)[i] = o;
  }
}

// ---------------------------------------------------------------------------
__global__ __launch_bounds__(256) void deg_count(
    const int* __restrict__ idx_i, int* __restrict__ deg, int E)
{
  const int stride = gridDim.x * blockDim.x;
  for (int e = blockIdx.x * blockDim.x + threadIdx.x; e < E; e += stride)
    atomicAdd(&deg[idx_i[e]], 1);
}

// ---------------------------------------------------------------------------
#define SCAN_B 64
#define SCAN_T (SCAN_B * 256)

__global__ __launch_bounds__(256) void deg_tsum(
    const int* __restrict__ deg, int* __restrict__ tsum, int N, int C)
{
  const int g = blockIdx.x * blockDim.x + threadIdx.x;
  const int lo = g * C;
  const int hi = (lo + C < N) ? (lo + C) : N;
  int s = 0;
  for (int i = lo; i < hi; ++i) s += deg[i];
  tsum[g] = s;
}

__global__ __launch_bounds__(256) void scan_tsum(int* __restrict__ tsum)
{
  __shared__ int ps[256];
  const int t = threadIdx.x;
  const int per = SCAN_T / 256;
  const int lo = t * per;
  int s = 0;
  for (int i = 0; i < per; ++i) s += tsum[lo + i];
  ps[t] = s;
  __syncthreads();
  if (t == 0) {
    int a = 0;
    for (int i = 0; i < 256; ++i) { const int v = ps[i]; ps[i] = a; a += v; }
  }
  __syncthreads();
  int acc = ps[t];
  for (int i = 0; i < per; ++i) {
    const int v = tsum[lo + i];
    tsum[lo + i] = acc;
    acc += v;
  }
}

__global__ __launch_bounds__(256) void write_csr(
    const int* __restrict__ deg, const int* __restrict__ tpre,
    int* __restrict__ rowstart, int* __restrict__ cursor,
    float* __restrict__ counts, int N, int C)
{
  const int g = blockIdx.x * blockDim.x + threadIdx.x;
  const int lo = g * C;
  const int hi = (lo + C < N) ? (lo + C) : N;
  int acc = tpre[g];
  for (int i = lo; i < hi; ++i) {
    const int d = deg[i];
    rowstart[i] = acc;
    cursor[i] = acc;
    counts[i] = (float)d;
    acc += d;
  }
  if (hi == N) rowstart[N] = acc;
}

// ---------------------------------------------------------------------------
__global__ __launch_bounds__(256) void bucket_edges(
    const int* __restrict__ idx_i, const int* __restrict__ idx_j,
    int* __restrict__ cursor, int* __restrict__ iperm,
    int* __restrict__ jperm, int E)
{
  const int stride = gridDim.x * blockDim.x;
  for (int e = blockIdx.x * blockDim.x + threadIdx.x; e < E; e += stride) {
    const int ii = idx_i[e];
    const int pos = atomicAdd(&cursor[ii], 1);
    iperm[pos] = ii;
    jperm[pos] = idx_j[e];
  }
}

// ---------------------------------------------------------------------------
// F12 (CSR order), 2-tile ILP: each wave runs two independent 16-edge tiles
// (A,B) per iteration with separate transpose buffers -> two independent
// dependency chains per stall window (kernel is latency-bound at ~23%
// achieved occupancy; TLP knobs were exhausted rounds 11-12).
// ---------------------------------------------------------------------------
#define THS 72
__global__ __launch_bounds__(256) void edge_f12(
    const ushort_t* __restrict__ h_bf, const float* __restrict__ x,
    const int* __restrict__ iperm, const int* __restrict__ jperm,
    const float* __restrict__ W_in, const float* __restrict__ b_in,
    const float* __restrict__ W_h, const float* __restrict__ b_h,
    const float* __restrict__ W_out, const float* __restrict__ b_out,
    const float* __restrict__ W_att, const float* __restrict__ b_att,
    float* __restrict__ dirb, ushort_t* __restrict__ heb,
    float* __restrict__ expl, float* __restrict__ denom, int E)
{
  __shared__ ushort_t sB1[8 * 512];     // 8 KB: W_in fragments
  __shared__ ushort_t sB2[20 * 512];    // 20 KB: W_h fragments
  __shared__ ushort_t tHA[4][16 * THS]; // 9 KB: tile-A transpose
  __shared__ ushort_t tHB[4][16 * THS]; // 9 KB: tile-B transpose

  const int tid = threadIdx.x;
  for (int idx = tid; idx < 8 * 512; idx += 256) {
    const int j = idx & 7;
    const int ln = (idx >> 3) & 63;
    const int f = idx >> 9;
    const int k = (f >> 1) * 32 + (ln >> 4) * 8 + j;
    const int col = (f & 1) * 16 + (ln & 15);
    sB1[idx] = (col < 20) ? f2bfu(W_in[k * 20 + col]) : (ushort_t)0;
  }
  for (int idx = tid; idx < 20 * 512; idx += 256) {
    const int j = idx & 7;
    const int ln = (idx >> 3) & 63;
    const int f = idx >> 9;
    const int k = (f >> 2) * 32 + (ln >> 4) * 8 + j;
    const int col = (f & 3) * 16 + (ln & 15);
    sB2[idx] = (k < 149) ? f2bfu(W_h[k * 64 + col]) : (ushort_t)0;
  }
  __syncthreads();

  const int gtid = blockIdx.x * blockDim.x + tid;
  const int wid = gtid >> 6;
  const int lane = tid & 63;
  const int w = tid >> 6;
  const int nw = (gridDim.x * blockDim.x) >> 6;
  const int l15 = lane & 15;
  const int q = lane >> 4;

  const ushort_t* b1l = sB1 + lane * 8;
  const ushort_t* b2l = sB2 + lane * 8;

  v8s bfr3[2][2];
  #pragma unroll
  for (int kc = 0; kc < 2; ++kc)
    #pragma unroll
    for (int nt = 0; nt < 2; ++nt)
      #pragma unroll
      for (int j = 0; j < 8; ++j) {
        const int k = kc * 32 + q * 8 + j;
        const int col = nt * 16 + l15;
        bfr3[kc][nt][j] = f2bfs(W_out[k * 32 + col]);
      }

  float bin[2], mu[2];
  #pragma unroll
  for (int nt = 0; nt < 2; ++nt) {
    const int col = nt * 16 + l15;
    bin[nt] = (col < 20) ? b_in[col] : 0.0f;
    mu[nt] = MU0 + (float)col * DMU;
  }
  float bias2[4];
  #pragma unroll
  for (int nt = 0; nt < 4; ++nt) bias2[nt] = b_h[nt * 16 + l15];
  float bias3[2];
  #pragma unroll
  for (int nt = 0; nt < 2; ++nt) bias3[nt] = b_out[nt * 16 + l15];

  v8s battf;
  #pragma unroll
  for (int j = 0; j < 8; ++j)
    battf[j] = (l15 < 4) ? f2bfs(W_att[(q * 8 + j) * 4 + l15]) : (short)0;
  const float bav = (l15 < 4) ? b_att[l15] : 0.0f;

  const int ntiles = (E + 15) >> 4;

  for (int tA = wid; tA < ntiles; tA += 2 * nw) {
    const int tBr = tA + nw;
    const bool hasB = (tBr < ntiles);
    const int tB = hasB ? tBr : tA;

    // --- idx + gathers for both tiles (8 loads in flight) ---
    const int rowA = tA * 16 + l15;
    const int rowLA = (rowA < E) ? rowA : (E - 1);
    const int iiA = iperm[rowLA];
    const int jjA = jperm[rowLA];
    const int rowB = tB * 16 + l15;
    const int rowLB = (rowB < E) ? rowB : (E - 1);
    const int iiB = iperm[rowLB];
    const int jjB = jperm[rowLB];

    v8s afrA[4], afrB[4];
    afrA[0] = *(const v8s*)(h_bf + (size_t)iiA * 64 + q * 8);
    afrA[1] = *(const v8s*)(h_bf + (size_t)iiA * 64 + 32 + q * 8);
    afrA[2] = *(const v8s*)(h_bf + (size_t)jjA * 64 + q * 8);
    afrA[3] = *(const v8s*)(h_bf + (size_t)jjA * 64 + 32 + q * 8);
    afrB[0] = *(const v8s*)(h_bf + (size_t)iiB * 64 + q * 8);
    afrB[1] = *(const v8s*)(h_bf + (size_t)iiB * 64 + 32 + q * 8);
    afrB[2] = *(const v8s*)(h_bf + (size_t)jjB * 64 + q * 8);
    afrB[3] = *(const v8s*)(h_bf + (size_t)jjB * 64 + 32 + q * 8);

    // --- geometry ---
    float dvalA = 0.0f, dvalB = 0.0f;
    if (lane < 16) {
      if (rowA < E) {
        const float rx = x[jjA * 3 + 0] - x[iiA * 3 + 0];
        const float ry = x[jjA * 3 + 1] - x[iiA * 3 + 1];
        const float rz = x[jjA * 3 + 2] - x[iiA * 3 + 2];
        const float d = sqrtf(rx * rx + ry * ry + rz * rz + EPSC);
        dvalA = d;
        const float inv = 1.0f / (d + EPSC);
        dirb[rowA * 3 + 0] = rx * inv;
        dirb[rowA * 3 + 1] = ry * inv;
        dirb[rowA * 3 + 2] = rz * inv;
      }
      if (hasB && rowB < E) {
        const float rx = x[jjB * 3 + 0] - x[iiB * 3 + 0];
        const float ry = x[jjB * 3 + 1] - x[iiB * 3 + 1];
        const float rz = x[jjB * 3 + 2] - x[iiB * 3 + 2];
        const float d = sqrtf(rx * rx + ry * ry + rz * rz + EPSC);
        dvalB = d;
        const float inv = 1.0f / (d + EPSC);
        dirb[rowB * 3 + 0] = rx * inv;
        dirb[rowB * 3 + 1] = ry * inv;
        dirb[rowB * 3 + 2] = rz * inv;
      }
    }

    // --- M1 (A and B interleaved by scheduler) ---
    v4f acc1A[2], acc1B[2];
    #pragma unroll
    for (int nt = 0; nt < 2; ++nt) {
      v4f a = {0.f, 0.f, 0.f, 0.f};
      v4f b = {0.f, 0.f, 0.f, 0.f};
      #pragma unroll
      for (int kc = 0; kc < 4; ++kc) {
        const v8s bfrag = *(const v8s*)(b1l + (kc * 2 + nt) * 512);
        a = __builtin_amdgcn_mfma_f32_16x16x32_bf16(afrA[kc], bfrag, a, 0, 0, 0);
        b = __builtin_amdgcn_mfma_f32_16x16x32_bf16(afrB[kc], bfrag, b, 0, 0, 0);
      }
      acc1A[nt] = a;
      acc1B[nt] = b;
    }

    // --- RBF epilogues -> tHA / tHB ---
    float drA[4], edrA[4], drB[4], edrB[4];
    #pragma unroll
    for (int r = 0; r < 4; ++r) {
      drA[r] = __shfl(dvalA, q * 4 + r);
      edrA[r] = __expf(-drA[r]);
      drB[r] = __shfl(dvalB, q * 4 + r);
      edrB[r] = __expf(-drB[r]);
    }
    #pragma unroll
    for (int nt = 0; nt < 2; ++nt) {
      const int col = nt * 16 + l15;
      #pragma unroll
      for (int r = 0; r < 4; ++r) {
        ushort_t ovA, ovB;
        if (col < 20) {
          const float ta = edrA[r] - mu[nt];
          ovA = f2bfu((acc1A[nt][r] + bin[nt]) * __expf(-BETA * ta * ta));
          const float tb = edrB[r] - mu[nt];
          ovB = f2bfu((acc1B[nt][r] + bin[nt]) * __expf(-BETA * tb * tb));
        } else if (col == 20) {
          ovA = f2bfu(drA[r]);
          ovB = f2bfu(drB[r]);
        } else {
          ovA = 0; ovB = 0;
        }
        tHA[w][(q * 4 + r) * THS + col] = ovA;
        tHB[w][(q * 4 + r) * THS + col] = ovB;
      }
    }
    __builtin_amdgcn_wave_barrier();

    const v8s afr4A = *(const v8s*)&tHA[w][l15 * THS + q * 8];
    const v8s afr4B = *(const v8s*)&tHB[w][l15 * THS + q * 8];
    __builtin_amdgcn_wave_barrier();

    // --- M2 (A and B interleaved) ---
    v4f acc2A[4], acc2B[4];
    #pragma unroll
    for (int nt = 0; nt < 4; ++nt) {
      v4f a = {0.f, 0.f, 0.f, 0.f};
      v4f b = {0.f, 0.f, 0.f, 0.f};
      #pragma unroll
      for (int kc = 0; kc < 4; ++kc) {
        const v8s bfrag = *(const v8s*)(b2l + (kc * 4 + nt) * 512);
        a = __builtin_amdgcn_mfma_f32_16x16x32_bf16(afrA[kc], bfrag, a, 0, 0, 0);
        b = __builtin_amdgcn_mfma_f32_16x16x32_bf16(afrB[kc], bfrag, b, 0, 0, 0);
      }
      const v8s bfrag4 = *(const v8s*)(b2l + (4 * 4 + nt) * 512);
      a = __builtin_amdgcn_mfma_f32_16x16x32_bf16(afr4A, bfrag4, a, 0, 0, 0);
      b = __builtin_amdgcn_mfma_f32_16x16x32_bf16(afr4B, bfrag4, b, 0, 0, 0);
      acc2A[nt] = a;
      acc2B[nt] = b;
    }

    #pragma unroll
    for (int nt = 0; nt < 4; ++nt) {
      #pragma unroll
      for (int r = 0; r < 4; ++r) {
        tHA[w][(q * 4 + r) * THS + nt * 16 + l15] =
            f2bfu(siluf(acc2A[nt][r] + bias2[nt]));
        tHB[w][(q * 4 + r) * THS + nt * 16 + l15] =
            f2bfu(siluf(acc2B[nt][r] + bias2[nt]));
      }
    }
    __builtin_amdgcn_wave_barrier();

    v8s af3A[2], af3B[2];
    af3A[0] = *(const v8s*)&tHA[w][l15 * THS + q * 8];
    af3A[1] = *(const v8s*)&tHA[w][l15 * THS + 32 + q * 8];
    af3B[0] = *(const v8s*)&tHB[w][l15 * THS + q * 8];
    af3B[1] = *(const v8s*)&tHB[w][l15 * THS + 32 + q * 8];

    v4f acc3A[2], acc3B[2];
    #pragma unroll
    for (int nt = 0; nt < 2; ++nt) {
      v4f a = {0.f, 0.f, 0.f, 0.f};
      v4f b = {0.f, 0.f, 0.f, 0.f};
      #pragma unroll
      for (int kc = 0; kc < 2; ++kc) {
        a = __builtin_amdgcn_mfma_f32_16x16x32_bf16(af3A[kc], bfr3[kc][nt], a, 0, 0, 0);
        b = __builtin_amdgcn_mfma_f32_16x16x32_bf16(af3B[kc], bfr3[kc][nt], b, 0, 0, 0);
      }
      acc3A[nt] = a;
      acc3B[nt] = b;
    }
    __builtin_amdgcn_wave_barrier();

    const int rowbA = tA * 16 + q * 4;
    const int rowbB = tB * 16 + q * 4;
    #pragma unroll
    for (int nt = 0; nt < 2; ++nt) {
      const int col = nt * 16 + l15;
      #pragma unroll
      for (int r = 0; r < 4; ++r) {
        const ushort_t hvA = f2bfu(acc3A[nt][r] + bias3[nt]);
        tHA[w][(q * 4 + r) * THS + col] = hvA;
        if (rowbA + r < E) heb[(size_t)(rowbA + r) * 32 + col] = hvA;
        const ushort_t hvB = f2bfu(acc3B[nt][r] + bias3[nt]);
        tHB[w][(q * 4 + r) * THS + col] = hvB;
        if (hasB && rowbB + r < E) heb[(size_t)(rowbB + r) * 32 + col] = hvB;
      }
    }
    __builtin_amdgcn_wave_barrier();

    // --- att via MFMA, both tiles ---
    const v8s afAA = *(const v8s*)&tHA[w][l15 * THS + q * 8];
    const v8s afAB = *(const v8s*)&tHB[w][l15 * THS + q * 8];
    v4f az = {0.f, 0.f, 0.f, 0.f};
    const v4f aaccA = __builtin_amdgcn_mfma_f32_16x16x32_bf16(afAA, battf, az, 0, 0, 0);
    const v4f aaccB = __builtin_amdgcn_mfma_f32_16x16x32_bf16(afAB, battf, az, 0, 0, 0);

    int iiA_r[4], iiB_r[4];
    #pragma unroll
    for (int r = 0; r < 4; ++r) {
      iiA_r[r] = __shfl(iiA, q * 4 + r);
      iiB_r[r] = __shfl(iiB, q * 4 + r);
    }

    if (l15 < 4) {
      #pragma unroll
      for (int r = 0; r < 4; ++r) {
        if (rowbA + r < E) {
          const float la = aaccA[r] + bav;
          const float l = (la > 0.f) ? la : 2.0f * (__expf(0.5f * la) - 1.0f);
          const float ev = __expf(l);
          expl[(size_t)(rowbA + r) * 4 + l15] = ev;
          atomAddF(&denom[iiA_r[r] * 4 + l15], ev);
        }
        if (hasB && rowbB + r < E) {
          const float la = aaccB[r] + bav;
          const float l = (la > 0.f) ? la : 2.0f * (__expf(0.5f * la) - 1.0f);
          const float ev = __expf(l);
          expl[(size_t)(rowbB + r) * 4 + l15] = ev;
          atomAddF(&denom[iiB_r[r] * 4 + l15], ev);
        }
      }
    }
    __builtin_amdgcn_wave_barrier();
  }
}

// ---------------------------------------------------------------------------
// mix_kernel (CSR order)
// ---------------------------------------------------------------------------
__global__ __launch_bounds__(256) void mix_kernel(
    const ushort_t* __restrict__ heb, const int* __restrict__ iperm,
    const float* __restrict__ expl, const float* __restrict__ denom,
    const float* __restrict__ W_xmix, const float* __restrict__ w_vmix,
    ushort_t* __restrict__ mixE, float* __restrict__ pE, int E)
{
  const int tid = blockIdx.x * blockDim.x + threadIdx.x;
  const int wid = tid >> 6;
  const int lane = threadIdx.x & 63;
  const int nw = (gridDim.x * blockDim.x) >> 6;
  const int l15 = lane & 15;
  const int q = lane >> 4;

  v8s bfr[4][2];
  #pragma unroll
  for (int kc = 0; kc < 4; ++kc)
    #pragma unroll
    for (int nt = 0; nt < 2; ++nt)
      #pragma unroll
      for (int j = 0; j < 8; ++j) {
        const int k = kc * 32 + q * 8 + j;
        const int col = nt * 16 + l15;
        bfr[kc][nt][j] = f2bfs(W_xmix[k * 32 + col]);
      }
  float wv[2];
  wv[0] = w_vmix[l15];
  wv[1] = w_vmix[16 + l15];

  const int ntiles = (E + 15) >> 4;
  for (int t = wid; t < ntiles; t += nw) {
    const int row = t * 16 + l15;
    const int rowL = (row < E) ? row : (E - 1);
    const int ii = iperm[rowL];
    float att[4];
    #pragma unroll
    for (int hh = 0; hh < 4; ++hh)
      att[hh] = expl[(size_t)rowL * 4 + hh] / (denom[ii * 4 + hh] + EPSC);

    const v8s hech = *(const v8s*)(heb + (size_t)rowL * 32 + q * 8);
    float hef[8];
    #pragma unroll
    for (int j = 0; j < 8; ++j) hef[j] = bf2f((ushort_t)hech[j]);

    v8s afr[4];
    #pragma unroll
    for (int kc = 0; kc < 4; ++kc)
      #pragma unroll
      for (int j = 0; j < 8; ++j)
        afr[kc][j] = f2bfs(att[kc] * hef[j]);

    v4f acc[2];
    #pragma unroll
    for (int nt = 0; nt < 2; ++nt) {
      v4f a = {0.f, 0.f, 0.f, 0.f};
      #pragma unroll
      for (int kc = 0; kc < 4; ++kc)
        a = __builtin_amdgcn_mfma_f32_16x16x32_bf16(afr[kc], bfr[kc][nt], a, 0, 0, 0);
      acc[nt] = a;
    }

    const int rowb = t * 16 + q * 4;
    float pr[4];
    #pragma unroll
    for (int r = 0; r < 4; ++r) {
      const float m0 = tanhf(acc[0][r]);
      const float m1 = tanhf(acc[1][r]);
      if (rowb + r < E) {
        mixE[(size_t)(rowb + r) * 32 + l15] = f2bfu(m0);
        mixE[(size_t)(rowb + r) * 32 + 16 + l15] = f2bfu(m1);
      }
      pr[r] = m0 * wv[0] + m1 * wv[1];
    }
    #pragma unroll
    for (int r = 0; r < 4; ++r) {
      pr[r] += __shfl_xor(pr[r], 1);
      pr[r] += __shfl_xor(pr[r], 2);
      pr[r] += __shfl_xor(pr[r], 4);
      pr[r] += __shfl_xor(pr[r], 8);
      if (l15 == 0 && rowb + r < E) pE[rowb + r] = pr[r];
    }
  }
}

// ---------------------------------------------------------------------------
// node_reduce: wave per node, streaming CSR reads, 4x unrolled
// ---------------------------------------------------------------------------
__global__ __launch_bounds__(256) void node_reduce(
    const int* __restrict__ rowstart,
    const ushort_t* __restrict__ heb, const ushort_t* __restrict__ mixE,
    const float* __restrict__ expl, const float* __restrict__ denom,
    const float* __restrict__ dirb, const float* __restrict__ pE,
    ushort_t* __restrict__ hsem, float* __restrict__ comb_sum,
    float* __restrict__ dv_sum, int N)
{
  const int tid = blockIdx.x * blockDim.x + threadIdx.x;
  const int wid = tid >> 6;
  const int lane = threadIdx.x & 63;
  const int nw = (gridDim.x * blockDim.x) >> 6;
  const int hh = lane >> 5;
  const int eb = lane & 31;

  for (int n = wid; n < N; n += nw) {
    const int s = rowstart[n];
    const int epd = rowstart[n + 1];
    float semA = 0.f, semB = 0.f;
    float cx = 0.f, cy = 0.f, cz = 0.f;
    float dvx = 0.f, dvy = 0.f, dvz = 0.f;
    int k = s;
    const int e4 = s + ((epd - s) & ~3);
    for (; k < e4; k += 4) {
      float he[4], ea[4], ec[4], dx[4], dy[4], dz[4], m[4], pe[4];
      #pragma unroll
      for (int u = 0; u < 4; ++u) {
        he[u] = bf2f(heb[(size_t)(k + u) * 32 + eb]);
        ea[u] = expl[(size_t)(k + u) * 4 + hh];
        ec[u] = expl[(size_t)(k + u) * 4 + 2 + hh];
        dx[u] = dirb[(k + u) * 3 + 0];
        dy[u] = dirb[(k + u) * 3 + 1];
        dz[u] = dirb[(k + u) * 3 + 2];
      }
      if (lane < 32) {
        #pragma unroll
        for (int u = 0; u < 4; ++u)
          m[u] = bf2f(mixE[(size_t)(k + u) * 32 + lane]);
      }
      if (lane == 0) {
        #pragma unroll
        for (int u = 0; u < 4; ++u) pe[u] = pE[k + u];
      }
      #pragma unroll
      for (int u = 0; u < 4; ++u) {
        semA += ea[u] * he[u];
        semB += ec[u] * he[u];
        if (lane < 32) {
          cx += dx[u] * m[u]; cy += dy[u] * m[u]; cz += dz[u] * m[u];
        }
        if (lane == 0) {
          dvx += dx[u] * pe[u]; dvy += dy[u] * pe[u]; dvz += dz[u] * pe[u];
        }
      }
    }
    for (; k < epd; ++k) {
      const float he = bf2f(heb[(size_t)k * 32 + eb]);
      const float ea = expl[(size_t)k * 4 + hh];
      const float ec = expl[(size_t)k * 4 + 2 + hh];
      semA += ea * he;
      semB += ec * he;
      const float dx = dirb[k * 3 + 0];
      const float dy = dirb[k * 3 + 1];
      const float dz = dirb[k * 3 + 2];
      if (lane < 32) {
        const float m = bf2f(mixE[(size_t)k * 32 + lane]);
        cx += dx * m; cy += dy * m; cz += dz * m;
      }
      if (lane == 0) {
        const float pe = pE[k];
        dvx += dx * pe; dvy += dy * pe; dvz += dz * pe;
      }
    }
    const float dA = denom[n * 4 + hh] + EPSC;
    const float dB = denom[n * 4 + 2 + hh] + EPSC;
    hsem[(size_t)n * 128 + lane] = f2bfu(semA / dA);
    hsem[(size_t)n * 128 + 64 + lane] = f2bfu(semB / dB);
    if (lane < 32) {
      comb_sum[(size_t)n * 96 + lane * 3 + 0] = cx;
      comb_sum[(size_t)n * 96 + lane * 3 + 1] = cy;
      comb_sum[(size_t)n * 96 + lane * 3 + 2] = cz;
    }
    if (lane == 0) {
      dv_sum[n * 3 + 0] = dvx;
      dv_sum[n * 3 + 1] = dvy;
      dv_sum[n * 3 + 2] = dvz;
    }
  }
}

// ---------------------------------------------------------------------------
// C1 (MFMA): spatial MLP (post1/post2) + node1 -> nh bf16 [N,128]
// ---------------------------------------------------------------------------
#define W1S 232
__global__ __launch_bounds__(256) void node_c1_mfma(
    const ushort_t* __restrict__ h_bf, const ushort_t* __restrict__ hsem,
    const float* __restrict__ comb_sum, const float* __restrict__ counts,
    const float* __restrict__ W_post1, const float* __restrict__ b_post1,
    const float* __restrict__ W_post2, const float* __restrict__ b_post2,
    const float* __restrict__ W_node1, const float* __restrict__ b_node1,
    ushort_t* __restrict__ nh_out, int N)
{
  __shared__ ushort_t sW1t[128 * W1S];
  __shared__ ushort_t tp[4][16 * THS];

  const int tid = threadIdx.x;
  for (int idx = tid; idx < 224 * 128; idx += 256) {
    const int k = idx >> 7;
    const int c = idx & 127;
    sW1t[c * W1S + k] = f2bfu(W_node1[idx]);
  }
  __syncthreads();

  const int lane = tid & 63;
  const int w = tid >> 6;
  const int l15 = lane & 15;
  const int q = lane >> 4;

  v8s bp1[4];
  #pragma unroll
  for (int nt = 0; nt < 4; ++nt)
    #pragma unroll
    for (int j = 0; j < 8; ++j)
      bp1[nt][j] = f2bfs(W_post1[(q * 8 + j) * 64 + nt * 16 + l15]);
  v8s bp2[2][2];
  #pragma unroll
  for (int kc = 0; kc < 2; ++kc)
    #pragma unroll
    for (int nt = 0; nt < 2; ++nt)
      #pragma unroll
      for (int j = 0; j < 8; ++j)
        bp2[kc][nt][j] = f2bfs(W_post2[(kc * 32 + q * 8 + j) * 32 + nt * 16 + l15]);
  float bb1[4];
  #pragma unroll
  for (int nt = 0; nt < 4; ++nt) bb1[nt] = b_post1[nt * 16 + l15];
  float bb2[2];
  #pragma unroll
  for (int nt = 0; nt < 2; ++nt) bb2[nt] = b_post2[nt * 16 + l15];
  float b1[8];
  #pragma unroll
  for (int nt = 0; nt < 8; ++nt) b1[nt] = b_node1[nt * 16 + l15];

  const int gw = blockIdx.x * 4 + w;
  const int nwv = gridDim.x * 4;
  const int ntiles = (N + 15) >> 4;

  for (int t = gw; t < ntiles; t += nwv) {
    const int row = t * 16 + l15;
    const int rowL = (row < N) ? row : (N - 1);

    const float inv = 1.0f / fmaxf(counts[rowL], 1.0f);
    const float4* cs = (const float4*)(comb_sum + (size_t)rowL * 96 + q * 24);
    float cf[24];
    #pragma unroll
    for (int b = 0; b < 6; ++b) {
      const float4 cv = cs[b];
      cf[b * 4 + 0] = cv.x; cf[b * 4 + 1] = cv.y;
      cf[b * 4 + 2] = cv.z; cf[b * 4 + 3] = cv.w;
    }
    v8s a1;
    #pragma unroll
    for (int j = 0; j < 8; ++j) {
      const float vx = cf[j * 3 + 0] * inv;
      const float vy = cf[j * 3 + 1] * inv;
      const float vz = cf[j * 3 + 2] * inv;
      a1[j] = f2bfs(vx * vx + vy * vy + vz * vz);
    }

    v4f p1[4];
    #pragma unroll
    for (int nt = 0; nt < 4; ++nt) {
      v4f a = {0.f, 0.f, 0.f, 0.f};
      p1[nt] = __builtin_amdgcn_mfma_f32_16x16x32_bf16(a1, bp1[nt], a, 0, 0, 0);
    }
    #pragma unroll
    for (int nt = 0; nt < 4; ++nt)
      #pragma unroll
      for (int r = 0; r < 4; ++r)
        tp[w][(q * 4 + r) * THS + nt * 16 + l15] =
            f2bfu(siluf(p1[nt][r] + bb1[nt]));
    __builtin_amdgcn_wave_barrier();

    v8s a2[2];
    a2[0] = *(const v8s*)&tp[w][l15 * THS + q * 8];
    a2[1] = *(const v8s*)&tp[w][l15 * THS + 32 + q * 8];

    v4f p2[2];
    #pragma unroll
    for (int nt = 0; nt < 2; ++nt) {
      v4f a = {0.f, 0.f, 0.f, 0.f};
      #pragma unroll
      for (int kc = 0; kc < 2; ++kc)
        a = __builtin_amdgcn_mfma_f32_16x16x32_bf16(a2[kc], bp2[kc][nt], a, 0, 0, 0);
      p2[nt] = a;
    }
    __builtin_amdgcn_wave_barrier();
    #pragma unroll
    for (int nt = 0; nt < 2; ++nt)
      #pragma unroll
      for (int r = 0; r < 4; ++r)
        tp[w][(q * 4 + r) * THS + nt * 16 + l15] =
            f2bfu(siluf(p2[nt][r] + bb2[nt]));
    __builtin_amdgcn_wave_barrier();

    v8s af[7];
    af[0] = *(const v8s*)(h_bf + (size_t)rowL * 64 + q * 8);
    af[1] = *(const v8s*)(h_bf + (size_t)rowL * 64 + 32 + q * 8);
    #pragma unroll
    for (int kc = 0; kc < 4; ++kc)
      af[2 + kc] = *(const v8s*)(hsem + (size_t)rowL * 128 + kc * 32 + q * 8);
    af[6] = *(const v8s*)&tp[w][l15 * THS + q * 8];

    v4f acc[8];
    #pragma unroll
    for (int nt = 0; nt < 8; ++nt) acc[nt] = (v4f){0.f, 0.f, 0.f, 0.f};
    #pragma unroll
    for (int kc = 0; kc < 7; ++kc) {
      #pragma unroll
      for (int nt = 0; nt < 8; ++nt) {
        const v8s bfrag =
            *(const v8s*)&sW1t[(nt * 16 + l15) * W1S + kc * 32 + q * 8];
        acc[nt] = __builtin_amdgcn_mfma_f32_16x16x32_bf16(af[kc], bfrag, acc[nt], 0, 0, 0);
      }
    }

    const int rowb = t * 16 + q * 4;
    #pragma unroll
    for (int nt = 0; nt < 8; ++nt) {
      #pragma unroll
      for (int r = 0; r < 4; ++r)
        if (rowb + r < N)
          nh_out[(size_t)(rowb + r) * 128 + nt * 16 + l15] =
              f2bfu(siluf(acc[nt][r] + b1[nt]));
    }
  }
}

// ---------------------------------------------------------------------------
// C2 (MFMA): node2 + vel1 + gate + v/x update
// ---------------------------------------------------------------------------
__global__ __launch_bounds__(256) void node_c2_mfma(
    const float* __restrict__ h, const float* __restrict__ x,
    const float* __restrict__ v, const ushort_t* __restrict__ nh,
    const float* __restrict__ dv_sum, const float* __restrict__ counts,
    const float* __restrict__ W_node2, const float* __restrict__ b_node2,
    const float* __restrict__ W_vel1, const float* __restrict__ b_vel1,
    const float* __restrict__ W_vel2,
    float* __restrict__ out, int N)
{
  __shared__ ushort_t sW2[16 * 64 * 8];
  __shared__ ushort_t sWv[4 * 64 * 8];
  __shared__ ushort_t tH[4][16 * THS];
  __shared__ float sg[4][16];

  const int tid = threadIdx.x;
  for (int idx = tid; idx < 16 * 64 * 8; idx += 256) {
    const int j = idx & 7;
    const int ln = (idx >> 3) & 63;
    const int f = idx >> 9;
    const int k = (f >> 2) * 32 + (ln >> 4) * 8 + j;
    const int col = (f & 3) * 16 + (ln & 15);
    sW2[idx] = f2bfu(W_node2[k * 64 + col]);
  }
  for (int idx = tid; idx < 4 * 64 * 8; idx += 256) {
    const int j = idx & 7;
    const int ln = (idx >> 3) & 63;
    const int f = idx >> 9;
    const int k = (f >> 1) * 32 + (ln >> 4) * 8 + j;
    const int col = (f & 1) * 16 + (ln & 15);
    sWv[idx] = f2bfu(W_vel1[k * 32 + col]);
  }
  __syncthreads();

  const int lane = tid & 63;
  const int w = tid >> 6;
  const int l15 = lane & 15;
  const int q = lane >> 4;

  const ushort_t* w2l = sW2 + lane * 8;
  const ushort_t* wvl = sWv + lane * 8;

  float b2[4];
  #pragma unroll
  for (int nt = 0; nt < 4; ++nt) b2[nt] = b_node2[nt * 16 + l15];
  float bv[2];
  #pragma unroll
  for (int nt = 0; nt < 2; ++nt) bv[nt] = b_vel1[nt * 16 + l15];
  float wv2[2];
  #pragma unroll
  for (int nt = 0; nt < 2; ++nt) wv2[nt] = W_vel2[nt * 16 + l15];

  const int gw = blockIdx.x * 4 + w;
  const int nwv = gridDim.x * 4;
  const int ntiles = (N + 15) >> 4;

  for (int t = gw; t < ntiles; t += nwv) {
    const int row = t * 16 + l15;
    const int rowL = (row < N) ? row : (N - 1);

    v8s af[4];
    #pragma unroll
    for (int kc = 0; kc < 4; ++kc)
      af[kc] = *(const v8s*)(nh + (size_t)rowL * 128 + kc * 32 + q * 8);

    v4f acc[4];
    #pragma unroll
    for (int nt = 0; nt < 4; ++nt) {
      v4f a = {0.f, 0.f, 0.f, 0.f};
      #pragma unroll
      for (int kc = 0; kc < 4; ++kc) {
        const v8s bfrag = *(const v8s*)(w2l + (kc * 4 + nt) * 512);
        a = __builtin_amdgcn_mfma_f32_16x16x32_bf16(af[kc], bfrag, a, 0, 0, 0);
      }
      acc[nt] = a;
    }

    const int rowb = t * 16 + q * 4;
    #pragma unroll
    for (int nt = 0; nt < 4; ++nt) {
      const int col = nt * 16 + l15;
      #pragma unroll
      for (int r = 0; r < 4; ++r) {
        const int n = rowb + r;
        if (n < N) {
          const float hu = h[(size_t)n * 64 + col] + siluf(acc[nt][r] + b2[nt]);
          out[(size_t)n * 64 + col] = hu;
          tH[w][(q * 4 + r) * THS + col] = f2bfu(hu);
        }
      }
    }
    __builtin_amdgcn_wave_barrier();

    v8s a2[2];
    a2[0] = *(const v8s*)&tH[w][l15 * THS + q * 8];
    a2[1] = *(const v8s*)&tH[w][l15 * THS + 32 + q * 8];
    v4f av[2];
    #pragma unroll
    for (int nt = 0; nt < 2; ++nt) {
      v4f a = {0.f, 0.f, 0.f, 0.f};
      #pragma unroll
      for (int kc = 0; kc < 2; ++kc) {
        const v8s bfrag = *(const v8s*)(wvl + (kc * 2 + nt) * 512);
        a = __builtin_amdgcn_mfma_f32_16x16x32_bf16(a2[kc], bfrag, a, 0, 0, 0);
      }
      av[nt] = a;
    }

    #pragma unroll
    for (int r = 0; r < 4; ++r) {
      float pr = siluf(av[0][r] + bv[0]) * wv2[0] +
                 siluf(av[1][r] + bv[1]) * wv2[1];
      pr += __shfl_xor(pr, 1);
      pr += __shfl_xor(pr, 2);
      pr += __shfl_xor(pr, 4);
      pr += __shfl_xor(pr, 8);
      if (l15 == 0) sg[w][q * 4 + r] = 2.0f / (1.0f + __expf(-pr));
    }
    __builtin_amdgcn_wave_barrier();

    if (lane < 48) {
      const int rr = lane / 3;
      const int c = lane % 3;
      const int n = t * 16 + rr;
      if (n < N) {
        const float gate = sg[w][rr];
        const float cnt = fmaxf(counts[n], 1.0f);
        const float dv = dv_sum[n * 3 + c] / cnt;
        const float vu = gate * v[n * 3 + c] + dv;
        out[(size_t)N * 64 + (size_t)n * 3 + c] = x[n * 3 + c] + vu;
        out[(size_t)N * 64 + (size_t)N * 3 + (size_t)n * 3 + c] = vu;
      }
    }
    __builtin_amdgcn_wave_barrier();
  }
}

// ---------------------------------------------------------------------------
extern "C" void kernel_launch(void* const* d_in, const int* in_sizes, int n_in,
                              void* d_out, int out_size, void* d_ws, size_t ws_size,
                              hipStream_t stream) {
  const float* h   = (const float*)d_in[0];
  const float* x   = (const float*)d_in[1];
  const float* v   = (const float*)d_in[2];
  const int* idx_i = (const int*)d_in[3];
  const int* idx_j = (const int*)d_in[4];
  const float* W_edge_in  = (const float*)d_in[5];
  const float* b_edge_in  = (const float*)d_in[6];
  const float* W_edge_h   = (const float*)d_in[7];
  const float* b_edge_h   = (const float*)d_in[8];
  const float* W_edge_out = (const float*)d_in[9];
  const float* b_edge_out = (const float*)d_in[10];
  const float* W_att      = (const float*)d_in[11];
  const float* b_att      = (const float*)d_in[12];
  const float* W_x_mix    = (const float*)d_in[13];
  const float* W_node1    = (const float*)d_in[14];
  const float* b_node1    = (const float*)d_in[15];
  const float* W_node2    = (const float*)d_in[16];
  const float* b_node2    = (const float*)d_in[17];
  const float* W_post1    = (const float*)d_in[18];
  const float* b_post1    = (const float*)d_in[19];
  const float* W_post2    = (const float*)d_in[20];
  const float* b_post2    = (const float*)d_in[21];
  const float* W_vel1     = (const float*)d_in[22];
  const float* b_vel1     = (const float*)d_in[23];
  const float* W_vel2     = (const float*)d_in[24];
  const float* w_v_mix    = (const float*)d_in[25];

  const int E = in_sizes[3];
  const int N = in_sizes[0] / DA;

  float* ws = (float*)d_ws;
  size_t off = 0;
  float* denom    = ws + off; off += (size_t)N * 4;     // zeroed
  int*   deg      = (int*)(ws + off); off += (size_t)N; // zeroed
  const size_t zeroBytes = off * sizeof(float);
  float* counts   = ws + off; off += (size_t)N;
  int*   rowstart = (int*)(ws + off); off += (size_t)N + 4;
  int*   cursor   = (int*)(ws + off); off += (size_t)N;
  int*   tsum     = (int*)(ws + off); off += (size_t)SCAN_T;
  int*   iperm    = (int*)(ws + off); off += (size_t)E;
  int*   jperm    = (int*)(ws + off); off += (size_t)E;
  float* pE       = ws + off; off += (size_t)E;
  float* expl     = ws + off; off += (size_t)E * 4;
  float* dirb     = ws + off; off += (size_t)E * 3;
  float* hsemR    = ws + off; off += (size_t)N * 64;
  float* comb_sum = ws + off; off += (size_t)N * 96;
  float* dv_sum   = ws + off; off += (size_t)N * 4;
  float* hbfR     = ws + off; off += (size_t)N * 32;
  float* fltR     = ws + off; off += (size_t)E * 16;    // mixE / nh
  float* hebR     = ws + off; off += (size_t)E * 16;

  ushort_t* h_bf = (ushort_t*)hbfR;
  ushort_t* hsem = (ushort_t*)hsemR;
  ushort_t* heb  = (ushort_t*)hebR;
  ushort_t* mixE = (ushort_t*)fltR;
  ushort_t* nh   = (ushort_t*)fltR;

  hipMemsetAsync(d_ws, 0, zeroBytes, stream);

  {
    const int n4 = (N * 64) / 4;
    cast_h<<<(n4 + 255) / 256, 256, 0, stream>>>(h, h_bf, n4);
  }
  deg_count<<<512, 256, 0, stream>>>(idx_i, deg, E);
  {
    const int C = (N + SCAN_T - 1) / SCAN_T;
    deg_tsum<<<SCAN_B, 256, 0, stream>>>(deg, tsum, N, C);
    scan_tsum<<<1, 256, 0, stream>>>(tsum);
    write_csr<<<SCAN_B, 256, 0, stream>>>(deg, tsum, rowstart, cursor, counts, N, C);
  }
  bucket_edges<<<512, 256, 0, stream>>>(idx_i, idx_j, cursor, iperm, jperm, E);
  edge_f12<<<1024, 256, 0, stream>>>(h_bf, x, iperm, jperm,
                                     W_edge_in, b_edge_in, W_edge_h, b_edge_h,
                                     W_edge_out, b_edge_out, W_att, b_att,
                                     dirb, heb, expl, denom, E);
  mix_kernel<<<1024, 256, 0, stream>>>(heb, iperm, expl, denom, W_x_mix,
                                       w_v_mix, mixE, pE, E);
  node_reduce<<<2048, 256, 0, stream>>>(rowstart, heb, mixE, expl, denom,
                                        dirb, pE, hsem, comb_sum, dv_sum, N);
  node_c1_mfma<<<512, 256, 0, stream>>>(
      h_bf, hsem, comb_sum, counts, W_post1, b_post1, W_post2, b_post2,
      W_node1, b_node1, nh, N);
  node_c2_mfma<<<512, 256, 0, stream>>>(
      h, x, v, nh, dv_sum, counts, W_node2, b_node2, W_vel1, b_vel1, W_vel2,
      (float*)d_out, N);
}

// Round 14
// 404.138 us; speedup vs baseline: 1.0315x; 1.0011x over previous
//
#include <hip/hip_runtime.h>
#include <math.h>

#define DA 64
#define NODEIN_DIM 224
#define EPSC 1e-8f

typedef short v8s __attribute__((ext_vector_type(8)));
typedef float v4f __attribute__((ext_vector_type(4)));
typedef unsigned short ushort_t;

__device__ __forceinline__ float siluf(float v) { return v / (1.0f + __expf(-v)); }

__device__ __forceinline__ void atomAddF(float* p, float v) {
#if defined(__HIP_DEVICE_COMPILE__)
  unsafeAtomicAdd(p, v);
#else
  atomicAdd(p, v);
#endif
}

__device__ __forceinline__ unsigned short f2bfu(float f) {
  union { float f; unsigned u; } v; v.f = f;
  unsigned r = v.u + 0x7fffu + ((v.u >> 16) & 1u);
  return (unsigned short)(r >> 16);
}
__device__ __forceinline__ short f2bfs(float f) { return (short)f2bfu(f); }
__device__ __forceinline__ float bf2f(ushort_t s) {
  union { unsigned u; float f; } v; v.u = ((unsigned)s) << 16; return v.f;
}

#define MU0 0.60653065971263342f
#define DMU ((1.0f - 0.60653065971263342f) / 19.0f)
#define BETA ((float)(1.0 / (0.039346934028736658 * 0.039346934028736658)))

// ---------------------------------------------------------------------------
__global__ __launch_bounds__(256) void cast_h(
    const float* __restrict__ hsrc, ushort_t* __restrict__ hb, int n4)
{
  const int i = blockIdx.x * blockDim.x + threadIdx.x;
  if (i < n4) {
    const float4 fv = ((const float4*)hsrc)[i];
    ushort4 o;
    o.x = f2bfu(fv.x); o.y = f2bfu(fv.y); o.z = f2bfu(fv.z); o.w = f2bfu(fv.w);
    ((ushort4*)hb)[i] = o;
  }
}

// ---------------------------------------------------------------------------
__global__ __launch_bounds__(256) void deg_count(
    const int* __restrict__ idx_i, int* __restrict__ deg, int E)
{
  const int stride = gridDim.x * blockDim.x;
  for (int e = blockIdx.x * blockDim.x + threadIdx.x; e < E; e += stride)
    atomicAdd(&deg[idx_i[e]], 1);
}

// ---------------------------------------------------------------------------
#define SCAN_B 64
#define SCAN_T (SCAN_B * 256)

__global__ __launch_bounds__(256) void deg_tsum(
    const int* __restrict__ deg, int* __restrict__ tsum, int N, int C)
{
  const int g = blockIdx.x * blockDim.x + threadIdx.x;
  const int lo = g * C;
  const int hi = (lo + C < N) ? (lo + C) : N;
  int s = 0;
  for (int i = lo; i < hi; ++i) s += deg[i];
  tsum[g] = s;
}

__global__ __launch_bounds__(256) void scan_tsum(int* __restrict__ tsum)
{
  __shared__ int ps[256];
  const int t = threadIdx.x;
  const int per = SCAN_T / 256;
  const int lo = t * per;
  int s = 0;
  for (int i = 0; i < per; ++i) s += tsum[lo + i];
  ps[t] = s;
  __syncthreads();
  if (t == 0) {
    int a = 0;
    for (int i = 0; i < 256; ++i) { const int v = ps[i]; ps[i] = a; a += v; }
  }
  __syncthreads();
  int acc = ps[t];
  for (int i = 0; i < per; ++i) {
    const int v = tsum[lo + i];
    tsum[lo + i] = acc;
    acc += v;
  }
}

__global__ __launch_bounds__(256) void write_csr(
    const int* __restrict__ deg, const int* __restrict__ tpre,
    int* __restrict__ rowstart, int* __restrict__ cursor,
    float* __restrict__ counts, int N, int C)
{
  const int g = blockIdx.x * blockDim.x + threadIdx.x;
  const int lo = g * C;
  const int hi = (lo + C < N) ? (lo + C) : N;
  int acc = tpre[g];
  for (int i = lo; i < hi; ++i) {
    const int d = deg[i];
    rowstart[i] = acc;
    cursor[i] = acc;
    counts[i] = (float)d;
    acc += d;
  }
  if (hi == N) rowstart[N] = acc;
}

// ---------------------------------------------------------------------------
__global__ __launch_bounds__(256) void bucket_edges(
    const int* __restrict__ idx_i, const int* __restrict__ idx_j,
    int* __restrict__ cursor, int* __restrict__ iperm,
    int* __restrict__ jperm, int E)
{
  const int stride = gridDim.x * blockDim.x;
  for (int e = blockIdx.x * blockDim.x + threadIdx.x; e < E; e += stride) {
    const int ii = idx_i[e];
    const int pos = atomicAdd(&cursor[ii], 1);
    iperm[pos] = ii;
    jperm[pos] = idx_j[e];
  }
}

// ---------------------------------------------------------------------------
// F12 (CSR order): best-measured config (round 12, 101 us): single tile,
// W_out fragments in registers, 2-deep software prefetch on gathers.
// Round-13's 2-tile ILP regressed (116 us: VGPR 84 serialized scheduling).
// ---------------------------------------------------------------------------
#define THS 72
__global__ __launch_bounds__(256) void edge_f12(
    const ushort_t* __restrict__ h_bf, const float* __restrict__ x,
    const int* __restrict__ iperm, const int* __restrict__ jperm,
    const float* __restrict__ W_in, const float* __restrict__ b_in,
    const float* __restrict__ W_h, const float* __restrict__ b_h,
    const float* __restrict__ W_out, const float* __restrict__ b_out,
    const float* __restrict__ W_att, const float* __restrict__ b_att,
    float* __restrict__ dirb, ushort_t* __restrict__ heb,
    float* __restrict__ expl, float* __restrict__ denom, int E)
{
  __shared__ ushort_t sB1[8 * 512];    // 8 KB: W_in fragments (kc*2+nt)
  __shared__ ushort_t sB2[20 * 512];   // 20 KB: W_h fragments (kc*4+nt)
  __shared__ ushort_t tH[4][16 * THS]; // 9 KB: per-wave transpose tile

  const int tid = threadIdx.x;
  for (int idx = tid; idx < 8 * 512; idx += 256) {
    const int j = idx & 7;
    const int ln = (idx >> 3) & 63;
    const int f = idx >> 9;
    const int k = (f >> 1) * 32 + (ln >> 4) * 8 + j;
    const int col = (f & 1) * 16 + (ln & 15);
    sB1[idx] = (col < 20) ? f2bfu(W_in[k * 20 + col]) : (ushort_t)0;
  }
  for (int idx = tid; idx < 20 * 512; idx += 256) {
    const int j = idx & 7;
    const int ln = (idx >> 3) & 63;
    const int f = idx >> 9;
    const int k = (f >> 2) * 32 + (ln >> 4) * 8 + j;
    const int col = (f & 3) * 16 + (ln & 15);
    sB2[idx] = (k < 149) ? f2bfu(W_h[k * 64 + col]) : (ushort_t)0;
  }
  __syncthreads();

  const int gtid = blockIdx.x * blockDim.x + tid;
  const int wid = gtid >> 6;
  const int lane = tid & 63;
  const int w = tid >> 6;
  const int nw = (gridDim.x * blockDim.x) >> 6;
  const int l15 = lane & 15;
  const int q = lane >> 4;

  const ushort_t* b1l = sB1 + lane * 8;
  const ushort_t* b2l = sB2 + lane * 8;

  v8s bfr3[2][2];
  #pragma unroll
  for (int kc = 0; kc < 2; ++kc)
    #pragma unroll
    for (int nt = 0; nt < 2; ++nt)
      #pragma unroll
      for (int j = 0; j < 8; ++j) {
        const int k = kc * 32 + q * 8 + j;
        const int col = nt * 16 + l15;
        bfr3[kc][nt][j] = f2bfs(W_out[k * 32 + col]);
      }

  float bin[2], mu[2];
  #pragma unroll
  for (int nt = 0; nt < 2; ++nt) {
    const int col = nt * 16 + l15;
    bin[nt] = (col < 20) ? b_in[col] : 0.0f;
    mu[nt] = MU0 + (float)col * DMU;
  }
  float bias2[4];
  #pragma unroll
  for (int nt = 0; nt < 4; ++nt) bias2[nt] = b_h[nt * 16 + l15];
  float bias3[2];
  #pragma unroll
  for (int nt = 0; nt < 2; ++nt) bias3[nt] = b_out[nt * 16 + l15];

  v8s battf;
  #pragma unroll
  for (int j = 0; j < 8; ++j)
    battf[j] = (l15 < 4) ? f2bfs(W_att[(q * 8 + j) * 4 + l15]) : (short)0;
  const float bav = (l15 < 4) ? b_att[l15] : 0.0f;

  const int ntiles = (E + 15) >> 4;

  int iiC = 0, jjC = 0;
  v8s afr[4];
  if (wid < ntiles) {
    const int row0 = wid * 16 + l15;
    const int rowL0 = (row0 < E) ? row0 : (E - 1);
    iiC = iperm[rowL0];
    jjC = jperm[rowL0];
    afr[0] = *(const v8s*)(h_bf + (size_t)iiC * 64 + q * 8);
    afr[1] = *(const v8s*)(h_bf + (size_t)iiC * 64 + 32 + q * 8);
    afr[2] = *(const v8s*)(h_bf + (size_t)jjC * 64 + q * 8);
    afr[3] = *(const v8s*)(h_bf + (size_t)jjC * 64 + 32 + q * 8);
  }

  for (int t = wid; t < ntiles; t += nw) {
    const int tn = t + nw;
    int iiN = 0, jjN = 0;
    v8s nfr[4];
    if (tn < ntiles) {
      const int rowN = tn * 16 + l15;
      const int rowLN = (rowN < E) ? rowN : (E - 1);
      iiN = iperm[rowLN];
      jjN = jperm[rowLN];
      nfr[0] = *(const v8s*)(h_bf + (size_t)iiN * 64 + q * 8);
      nfr[1] = *(const v8s*)(h_bf + (size_t)iiN * 64 + 32 + q * 8);
      nfr[2] = *(const v8s*)(h_bf + (size_t)jjN * 64 + q * 8);
      nfr[3] = *(const v8s*)(h_bf + (size_t)jjN * 64 + 32 + q * 8);
    }

    const int row = t * 16 + l15;
    float dval = 0.0f;
    if (lane < 16 && row < E) {
      const float rx = x[jjC * 3 + 0] - x[iiC * 3 + 0];
      const float ry = x[jjC * 3 + 1] - x[iiC * 3 + 1];
      const float rz = x[jjC * 3 + 2] - x[iiC * 3 + 2];
      const float d = sqrtf(rx * rx + ry * ry + rz * rz + EPSC);
      dval = d;
      const float inv = 1.0f / (d + EPSC);
      dirb[row * 3 + 0] = rx * inv;
      dirb[row * 3 + 1] = ry * inv;
      dirb[row * 3 + 2] = rz * inv;
    }

    // M1: [16,128] x W_in
    v4f acc1[2];
    #pragma unroll
    for (int nt = 0; nt < 2; ++nt) {
      v4f a = {0.f, 0.f, 0.f, 0.f};
      #pragma unroll
      for (int kc = 0; kc < 4; ++kc) {
        const v8s bfrag = *(const v8s*)(b1l + (kc * 2 + nt) * 512);
        a = __builtin_amdgcn_mfma_f32_16x16x32_bf16(afr[kc], bfrag, a, 0, 0, 0);
      }
      acc1[nt] = a;
    }

    float dr[4], edr[4];
    #pragma unroll
    for (int r = 0; r < 4; ++r) {
      dr[r] = __shfl(dval, q * 4 + r);
      edr[r] = __expf(-dr[r]);
    }
    #pragma unroll
    for (int nt = 0; nt < 2; ++nt) {
      const int col = nt * 16 + l15;
      #pragma unroll
      for (int r = 0; r < 4; ++r) {
        ushort_t ov;
        if (col < 20) {
          const float tt = edr[r] - mu[nt];
          ov = f2bfu((acc1[nt][r] + bin[nt]) * __expf(-BETA * tt * tt));
        } else if (col == 20) {
          ov = f2bfu(dr[r]);
        } else {
          ov = 0;
        }
        tH[w][(q * 4 + r) * THS + col] = ov;
      }
    }
    __builtin_amdgcn_wave_barrier();

    const v8s afr4 = *(const v8s*)&tH[w][l15 * THS + q * 8];
    __builtin_amdgcn_wave_barrier();

    // M2: [16,160] x W_h
    v4f acc2[4];
    #pragma unroll
    for (int nt = 0; nt < 4; ++nt) {
      v4f a = {0.f, 0.f, 0.f, 0.f};
      #pragma unroll
      for (int kc = 0; kc < 4; ++kc) {
        const v8s bfrag = *(const v8s*)(b2l + (kc * 4 + nt) * 512);
        a = __builtin_amdgcn_mfma_f32_16x16x32_bf16(afr[kc], bfrag, a, 0, 0, 0);
      }
      const v8s bfrag4 = *(const v8s*)(b2l + (4 * 4 + nt) * 512);
      a = __builtin_amdgcn_mfma_f32_16x16x32_bf16(afr4, bfrag4, a, 0, 0, 0);
      acc2[nt] = a;
    }

    #pragma unroll
    for (int nt = 0; nt < 4; ++nt) {
      #pragma unroll
      for (int r = 0; r < 4; ++r)
        tH[w][(q * 4 + r) * THS + nt * 16 + l15] =
            f2bfu(siluf(acc2[nt][r] + bias2[nt]));
    }
    __builtin_amdgcn_wave_barrier();

    v8s af3[2];
    af3[0] = *(const v8s*)&tH[w][l15 * THS + q * 8];
    af3[1] = *(const v8s*)&tH[w][l15 * THS + 32 + q * 8];

    v4f acc3[2];
    #pragma unroll
    for (int nt = 0; nt < 2; ++nt) {
      v4f a = {0.f, 0.f, 0.f, 0.f};
      #pragma unroll
      for (int kc = 0; kc < 2; ++kc)
        a = __builtin_amdgcn_mfma_f32_16x16x32_bf16(af3[kc], bfr3[kc][nt], a, 0, 0, 0);
      acc3[nt] = a;
    }
    __builtin_amdgcn_wave_barrier();

    const int rowb = t * 16 + q * 4;
    #pragma unroll
    for (int nt = 0; nt < 2; ++nt) {
      const int col = nt * 16 + l15;
      #pragma unroll
      for (int r = 0; r < 4; ++r) {
        const ushort_t hv = f2bfu(acc3[nt][r] + bias3[nt]);
        tH[w][(q * 4 + r) * THS + col] = hv;
        if (rowb + r < E) heb[(size_t)(rowb + r) * 32 + col] = hv;
      }
    }
    __builtin_amdgcn_wave_barrier();

    const v8s afA = *(const v8s*)&tH[w][l15 * THS + q * 8];
    v4f az = {0.f, 0.f, 0.f, 0.f};
    const v4f aacc = __builtin_amdgcn_mfma_f32_16x16x32_bf16(afA, battf, az, 0, 0, 0);

    int ii_r[4];
    #pragma unroll
    for (int r = 0; r < 4; ++r) ii_r[r] = __shfl(iiC, q * 4 + r);

    if (l15 < 4) {
      #pragma unroll
      for (int r = 0; r < 4; ++r) {
        if (rowb + r < E) {
          const float la = aacc[r] + bav;
          const float l = (la > 0.f) ? la : 2.0f * (__expf(0.5f * la) - 1.0f);
          const float ev = __expf(l);
          expl[(size_t)(rowb + r) * 4 + l15] = ev;
          atomAddF(&denom[ii_r[r] * 4 + l15], ev);
        }
      }
    }
    __builtin_amdgcn_wave_barrier();

    iiC = iiN; jjC = jjN;
    afr[0] = nfr[0]; afr[1] = nfr[1]; afr[2] = nfr[2]; afr[3] = nfr[3];
  }
}

// ---------------------------------------------------------------------------
// mix_kernel (CSR order)
// ---------------------------------------------------------------------------
__global__ __launch_bounds__(256) void mix_kernel(
    const ushort_t* __restrict__ heb, const int* __restrict__ iperm,
    const float* __restrict__ expl, const float* __restrict__ denom,
    const float* __restrict__ W_xmix, const float* __restrict__ w_vmix,
    ushort_t* __restrict__ mixE, float* __restrict__ pE, int E)
{
  const int tid = blockIdx.x * blockDim.x + threadIdx.x;
  const int wid = tid >> 6;
  const int lane = threadIdx.x & 63;
  const int nw = (gridDim.x * blockDim.x) >> 6;
  const int l15 = lane & 15;
  const int q = lane >> 4;

  v8s bfr[4][2];
  #pragma unroll
  for (int kc = 0; kc < 4; ++kc)
    #pragma unroll
    for (int nt = 0; nt < 2; ++nt)
      #pragma unroll
      for (int j = 0; j < 8; ++j) {
        const int k = kc * 32 + q * 8 + j;
        const int col = nt * 16 + l15;
        bfr[kc][nt][j] = f2bfs(W_xmix[k * 32 + col]);
      }
  float wv[2];
  wv[0] = w_vmix[l15];
  wv[1] = w_vmix[16 + l15];

  const int ntiles = (E + 15) >> 4;
  for (int t = wid; t < ntiles; t += nw) {
    const int row = t * 16 + l15;
    const int rowL = (row < E) ? row : (E - 1);
    const int ii = iperm[rowL];
    float att[4];
    #pragma unroll
    for (int hh = 0; hh < 4; ++hh)
      att[hh] = expl[(size_t)rowL * 4 + hh] / (denom[ii * 4 + hh] + EPSC);

    const v8s hech = *(const v8s*)(heb + (size_t)rowL * 32 + q * 8);
    float hef[8];
    #pragma unroll
    for (int j = 0; j < 8; ++j) hef[j] = bf2f((ushort_t)hech[j]);

    v8s afr[4];
    #pragma unroll
    for (int kc = 0; kc < 4; ++kc)
      #pragma unroll
      for (int j = 0; j < 8; ++j)
        afr[kc][j] = f2bfs(att[kc] * hef[j]);

    v4f acc[2];
    #pragma unroll
    for (int nt = 0; nt < 2; ++nt) {
      v4f a = {0.f, 0.f, 0.f, 0.f};
      #pragma unroll
      for (int kc = 0; kc < 4; ++kc)
        a = __builtin_amdgcn_mfma_f32_16x16x32_bf16(afr[kc], bfr[kc][nt], a, 0, 0, 0);
      acc[nt] = a;
    }

    const int rowb = t * 16 + q * 4;
    float pr[4];
    #pragma unroll
    for (int r = 0; r < 4; ++r) {
      const float m0 = tanhf(acc[0][r]);
      const float m1 = tanhf(acc[1][r]);
      if (rowb + r < E) {
        mixE[(size_t)(rowb + r) * 32 + l15] = f2bfu(m0);
        mixE[(size_t)(rowb + r) * 32 + 16 + l15] = f2bfu(m1);
      }
      pr[r] = m0 * wv[0] + m1 * wv[1];
    }
    #pragma unroll
    for (int r = 0; r < 4; ++r) {
      pr[r] += __shfl_xor(pr[r], 1);
      pr[r] += __shfl_xor(pr[r], 2);
      pr[r] += __shfl_xor(pr[r], 4);
      pr[r] += __shfl_xor(pr[r], 8);
      if (l15 == 0 && rowb + r < E) pE[rowb + r] = pr[r];
    }
  }
}

// ---------------------------------------------------------------------------
// node_reduce: wave per node, streaming CSR reads, 4x unrolled
// ---------------------------------------------------------------------------
__global__ __launch_bounds__(256) void node_reduce(
    const int* __restrict__ rowstart,
    const ushort_t* __restrict__ heb, const ushort_t* __restrict__ mixE,
    const float* __restrict__ expl, const float* __restrict__ denom,
    const float* __restrict__ dirb, const float* __restrict__ pE,
    ushort_t* __restrict__ hsem, float* __restrict__ comb_sum,
    float* __restrict__ dv_sum, int N)
{
  const int tid = blockIdx.x * blockDim.x + threadIdx.x;
  const int wid = tid >> 6;
  const int lane = threadIdx.x & 63;
  const int nw = (gridDim.x * blockDim.x) >> 6;
  const int hh = lane >> 5;
  const int eb = lane & 31;

  for (int n = wid; n < N; n += nw) {
    const int s = rowstart[n];
    const int epd = rowstart[n + 1];
    float semA = 0.f, semB = 0.f;
    float cx = 0.f, cy = 0.f, cz = 0.f;
    float dvx = 0.f, dvy = 0.f, dvz = 0.f;
    int k = s;
    const int e4 = s + ((epd - s) & ~3);
    for (; k < e4; k += 4) {
      float he[4], ea[4], ec[4], dx[4], dy[4], dz[4], m[4], pe[4];
      #pragma unroll
      for (int u = 0; u < 4; ++u) {
        he[u] = bf2f(heb[(size_t)(k + u) * 32 + eb]);
        ea[u] = expl[(size_t)(k + u) * 4 + hh];
        ec[u] = expl[(size_t)(k + u) * 4 + 2 + hh];
        dx[u] = dirb[(k + u) * 3 + 0];
        dy[u] = dirb[(k + u) * 3 + 1];
        dz[u] = dirb[(k + u) * 3 + 2];
      }
      if (lane < 32) {
        #pragma unroll
        for (int u = 0; u < 4; ++u)
          m[u] = bf2f(mixE[(size_t)(k + u) * 32 + lane]);
      }
      if (lane == 0) {
        #pragma unroll
        for (int u = 0; u < 4; ++u) pe[u] = pE[k + u];
      }
      #pragma unroll
      for (int u = 0; u < 4; ++u) {
        semA += ea[u] * he[u];
        semB += ec[u] * he[u];
        if (lane < 32) {
          cx += dx[u] * m[u]; cy += dy[u] * m[u]; cz += dz[u] * m[u];
        }
        if (lane == 0) {
          dvx += dx[u] * pe[u]; dvy += dy[u] * pe[u]; dvz += dz[u] * pe[u];
        }
      }
    }
    for (; k < epd; ++k) {
      const float he = bf2f(heb[(size_t)k * 32 + eb]);
      const float ea = expl[(size_t)k * 4 + hh];
      const float ec = expl[(size_t)k * 4 + 2 + hh];
      semA += ea * he;
      semB += ec * he;
      const float dx = dirb[k * 3 + 0];
      const float dy = dirb[k * 3 + 1];
      const float dz = dirb[k * 3 + 2];
      if (lane < 32) {
        const float m = bf2f(mixE[(size_t)k * 32 + lane]);
        cx += dx * m; cy += dy * m; cz += dz * m;
      }
      if (lane == 0) {
        const float pe = pE[k];
        dvx += dx * pe; dvy += dy * pe; dvz += dz * pe;
      }
    }
    const float dA = denom[n * 4 + hh] + EPSC;
    const float dB = denom[n * 4 + 2 + hh] + EPSC;
    hsem[(size_t)n * 128 + lane] = f2bfu(semA / dA);
    hsem[(size_t)n * 128 + 64 + lane] = f2bfu(semB / dB);
    if (lane < 32) {
      comb_sum[(size_t)n * 96 + lane * 3 + 0] = cx;
      comb_sum[(size_t)n * 96 + lane * 3 + 1] = cy;
      comb_sum[(size_t)n * 96 + lane * 3 + 2] = cz;
    }
    if (lane == 0) {
      dv_sum[n * 3 + 0] = dvx;
      dv_sum[n * 3 + 1] = dvy;
      dv_sum[n * 3 + 2] = dvz;
    }
  }
}

// ---------------------------------------------------------------------------
// C1 (MFMA): spatial MLP (post1/post2) + node1 -> nh bf16 [N,128]
// ---------------------------------------------------------------------------
#define W1S 232
__global__ __launch_bounds__(256) void node_c1_mfma(
    const ushort_t* __restrict__ h_bf, const ushort_t* __restrict__ hsem,
    const float* __restrict__ comb_sum, const float* __restrict__ counts,
    const float* __restrict__ W_post1, const float* __restrict__ b_post1,
    const float* __restrict__ W_post2, const float* __restrict__ b_post2,
    const float* __restrict__ W_node1, const float* __restrict__ b_node1,
    ushort_t* __restrict__ nh_out, int N)
{
  __shared__ ushort_t sW1t[128 * W1S];
  __shared__ ushort_t tp[4][16 * THS];

  const int tid = threadIdx.x;
  for (int idx = tid; idx < 224 * 128; idx += 256) {
    const int k = idx >> 7;
    const int c = idx & 127;
    sW1t[c * W1S + k] = f2bfu(W_node1[idx]);
  }
  __syncthreads();

  const int lane = tid & 63;
  const int w = tid >> 6;
  const int l15 = lane & 15;
  const int q = lane >> 4;

  v8s bp1[4];
  #pragma unroll
  for (int nt = 0; nt < 4; ++nt)
    #pragma unroll
    for (int j = 0; j < 8; ++j)
      bp1[nt][j] = f2bfs(W_post1[(q * 8 + j) * 64 + nt * 16 + l15]);
  v8s bp2[2][2];
  #pragma unroll
  for (int kc = 0; kc < 2; ++kc)
    #pragma unroll
    for (int nt = 0; nt < 2; ++nt)
      #pragma unroll
      for (int j = 0; j < 8; ++j)
        bp2[kc][nt][j] = f2bfs(W_post2[(kc * 32 + q * 8 + j) * 32 + nt * 16 + l15]);
  float bb1[4];
  #pragma unroll
  for (int nt = 0; nt < 4; ++nt) bb1[nt] = b_post1[nt * 16 + l15];
  float bb2[2];
  #pragma unroll
  for (int nt = 0; nt < 2; ++nt) bb2[nt] = b_post2[nt * 16 + l15];
  float b1[8];
  #pragma unroll
  for (int nt = 0; nt < 8; ++nt) b1[nt] = b_node1[nt * 16 + l15];

  const int gw = blockIdx.x * 4 + w;
  const int nwv = gridDim.x * 4;
  const int ntiles = (N + 15) >> 4;

  for (int t = gw; t < ntiles; t += nwv) {
    const int row = t * 16 + l15;
    const int rowL = (row < N) ? row : (N - 1);

    const float inv = 1.0f / fmaxf(counts[rowL], 1.0f);
    const float4* cs = (const float4*)(comb_sum + (size_t)rowL * 96 + q * 24);
    float cf[24];
    #pragma unroll
    for (int b = 0; b < 6; ++b) {
      const float4 cv = cs[b];
      cf[b * 4 + 0] = cv.x; cf[b * 4 + 1] = cv.y;
      cf[b * 4 + 2] = cv.z; cf[b * 4 + 3] = cv.w;
    }
    v8s a1;
    #pragma unroll
    for (int j = 0; j < 8; ++j) {
      const float vx = cf[j * 3 + 0] * inv;
      const float vy = cf[j * 3 + 1] * inv;
      const float vz = cf[j * 3 + 2] * inv;
      a1[j] = f2bfs(vx * vx + vy * vy + vz * vz);
    }

    v4f p1[4];
    #pragma unroll
    for (int nt = 0; nt < 4; ++nt) {
      v4f a = {0.f, 0.f, 0.f, 0.f};
      p1[nt] = __builtin_amdgcn_mfma_f32_16x16x32_bf16(a1, bp1[nt], a, 0, 0, 0);
    }
    #pragma unroll
    for (int nt = 0; nt < 4; ++nt)
      #pragma unroll
      for (int r = 0; r < 4; ++r)
        tp[w][(q * 4 + r) * THS + nt * 16 + l15] =
            f2bfu(siluf(p1[nt][r] + bb1[nt]));
    __builtin_amdgcn_wave_barrier();

    v8s a2[2];
    a2[0] = *(const v8s*)&tp[w][l15 * THS + q * 8];
    a2[1] = *(const v8s*)&tp[w][l15 * THS + 32 + q * 8];

    v4f p2[2];
    #pragma unroll
    for (int nt = 0; nt < 2; ++nt) {
      v4f a = {0.f, 0.f, 0.f, 0.f};
      #pragma unroll
      for (int kc = 0; kc < 2; ++kc)
        a = __builtin_amdgcn_mfma_f32_16x16x32_bf16(a2[kc], bp2[kc][nt], a, 0, 0, 0);
      p2[nt] = a;
    }
    __builtin_amdgcn_wave_barrier();
    #pragma unroll
    for (int nt = 0; nt < 2; ++nt)
      #pragma unroll
      for (int r = 0; r < 4; ++r)
        tp[w][(q * 4 + r) * THS + nt * 16 + l15] =
            f2bfu(siluf(p2[nt][r] + bb2[nt]));
    __builtin_amdgcn_wave_barrier();

    v8s af[7];
    af[0] = *(const v8s*)(h_bf + (size_t)rowL * 64 + q * 8);
    af[1] = *(const v8s*)(h_bf + (size_t)rowL * 64 + 32 + q * 8);
    #pragma unroll
    for (int kc = 0; kc < 4; ++kc)
      af[2 + kc] = *(const v8s*)(hsem + (size_t)rowL * 128 + kc * 32 + q * 8);
    af[6] = *(const v8s*)&tp[w][l15 * THS + q * 8];

    v4f acc[8];
    #pragma unroll
    for (int nt = 0; nt < 8; ++nt) acc[nt] = (v4f){0.f, 0.f, 0.f, 0.f};
    #pragma unroll
    for (int kc = 0; kc < 7; ++kc) {
      #pragma unroll
      for (int nt = 0; nt < 8; ++nt) {
        const v8s bfrag =
            *(const v8s*)&sW1t[(nt * 16 + l15) * W1S + kc * 32 + q * 8];
        acc[nt] = __builtin_amdgcn_mfma_f32_16x16x32_bf16(af[kc], bfrag, acc[nt], 0, 0, 0);
      }
    }

    const int rowb = t * 16 + q * 4;
    #pragma unroll
    for (int nt = 0; nt < 8; ++nt) {
      #pragma unroll
      for (int r = 0; r < 4; ++r)
        if (rowb + r < N)
          nh_out[(size_t)(rowb + r) * 128 + nt * 16 + l15] =
              f2bfu(siluf(acc[nt][r] + b1[nt]));
    }
  }
}

// ---------------------------------------------------------------------------
// C2 (MFMA): node2 + vel1 + gate + v/x update
// ---------------------------------------------------------------------------
__global__ __launch_bounds__(256) void node_c2_mfma(
    const float* __restrict__ h, const float* __restrict__ x,
    const float* __restrict__ v, const ushort_t* __restrict__ nh,
    const float* __restrict__ dv_sum, const float* __restrict__ counts,
    const float* __restrict__ W_node2, const float* __restrict__ b_node2,
    const float* __restrict__ W_vel1, const float* __restrict__ b_vel1,
    const float* __restrict__ W_vel2,
    float* __restrict__ out, int N)
{
  __shared__ ushort_t sW2[16 * 64 * 8];
  __shared__ ushort_t sWv[4 * 64 * 8];
  __shared__ ushort_t tH[4][16 * THS];
  __shared__ float sg[4][16];

  const int tid = threadIdx.x;
  for (int idx = tid; idx < 16 * 64 * 8; idx += 256) {
    const int j = idx & 7;
    const int ln = (idx >> 3) & 63;
    const int f = idx >> 9;
    const int k = (f >> 2) * 32 + (ln >> 4) * 8 + j;
    const int col = (f & 3) * 16 + (ln & 15);
    sW2[idx] = f2bfu(W_node2[k * 64 + col]);
  }
  for (int idx = tid; idx < 4 * 64 * 8; idx += 256) {
    const int j = idx & 7;
    const int ln = (idx >> 3) & 63;
    const int f = idx >> 9;
    const int k = (f >> 1) * 32 + (ln >> 4) * 8 + j;
    const int col = (f & 1) * 16 + (ln & 15);
    sWv[idx] = f2bfu(W_vel1[k * 32 + col]);
  }
  __syncthreads();

  const int lane = tid & 63;
  const int w = tid >> 6;
  const int l15 = lane & 15;
  const int q = lane >> 4;

  const ushort_t* w2l = sW2 + lane * 8;
  const ushort_t* wvl = sWv + lane * 8;

  float b2[4];
  #pragma unroll
  for (int nt = 0; nt < 4; ++nt) b2[nt] = b_node2[nt * 16 + l15];
  float bv[2];
  #pragma unroll
  for (int nt = 0; nt < 2; ++nt) bv[nt] = b_vel1[nt * 16 + l15];
  float wv2[2];
  #pragma unroll
  for (int nt = 0; nt < 2; ++nt) wv2[nt] = W_vel2[nt * 16 + l15];

  const int gw = blockIdx.x * 4 + w;
  const int nwv = gridDim.x * 4;
  const int ntiles = (N + 15) >> 4;

  for (int t = gw; t < ntiles; t += nwv) {
    const int row = t * 16 + l15;
    const int rowL = (row < N) ? row : (N - 1);

    v8s af[4];
    #pragma unroll
    for (int kc = 0; kc < 4; ++kc)
      af[kc] = *(const v8s*)(nh + (size_t)rowL * 128 + kc * 32 + q * 8);

    v4f acc[4];
    #pragma unroll
    for (int nt = 0; nt < 4; ++nt) {
      v4f a = {0.f, 0.f, 0.f, 0.f};
      #pragma unroll
      for (int kc = 0; kc < 4; ++kc) {
        const v8s bfrag = *(const v8s*)(w2l + (kc * 4 + nt) * 512);
        a = __builtin_amdgcn_mfma_f32_16x16x32_bf16(af[kc], bfrag, a, 0, 0, 0);
      }
      acc[nt] = a;
    }

    const int rowb = t * 16 + q * 4;
    #pragma unroll
    for (int nt = 0; nt < 4; ++nt) {
      const int col = nt * 16 + l15;
      #pragma unroll
      for (int r = 0; r < 4; ++r) {
        const int n = rowb + r;
        if (n < N) {
          const float hu = h[(size_t)n * 64 + col] + siluf(acc[nt][r] + b2[nt]);
          out[(size_t)n * 64 + col] = hu;
          tH[w][(q * 4 + r) * THS + col] = f2bfu(hu);
        }
      }
    }
    __builtin_amdgcn_wave_barrier();

    v8s a2[2];
    a2[0] = *(const v8s*)&tH[w][l15 * THS + q * 8];
    a2[1] = *(const v8s*)&tH[w][l15 * THS + 32 + q * 8];
    v4f av[2];
    #pragma unroll
    for (int nt = 0; nt < 2; ++nt) {
      v4f a = {0.f, 0.f, 0.f, 0.f};
      #pragma unroll
      for (int kc = 0; kc < 2; ++kc) {
        const v8s bfrag = *(const v8s*)(wvl + (kc * 2 + nt) * 512);
        a = __builtin_amdgcn_mfma_f32_16x16x32_bf16(a2[kc], bfrag, a, 0, 0, 0);
      }
      av[nt] = a;
    }

    #pragma unroll
    for (int r = 0; r < 4; ++r) {
      float pr = siluf(av[0][r] + bv[0]) * wv2[0] +
                 siluf(av[1][r] + bv[1]) * wv2[1];
      pr += __shfl_xor(pr, 1);
      pr += __shfl_xor(pr, 2);
      pr += __shfl_xor(pr, 4);
      pr += __shfl_xor(pr, 8);
      if (l15 == 0) sg[w][q * 4 + r] = 2.0f / (1.0f + __expf(-pr));
    }
    __builtin_amdgcn_wave_barrier();

    if (lane < 48) {
      const int rr = lane / 3;
      const int c = lane % 3;
      const int n = t * 16 + rr;
      if (n < N) {
        const float gate = sg[w][rr];
        const float cnt = fmaxf(counts[n], 1.0f);
        const float dv = dv_sum[n * 3 + c] / cnt;
        const float vu = gate * v[n * 3 + c] + dv;
        out[(size_t)N * 64 + (size_t)n * 3 + c] = x[n * 3 + c] + vu;
        out[(size_t)N * 64 + (size_t)N * 3 + (size_t)n * 3 + c] = vu;
      }
    }
    __builtin_amdgcn_wave_barrier();
  }
}

// ---------------------------------------------------------------------------
extern "C" void kernel_launch(void* const* d_in, const int* in_sizes, int n_in,
                              void* d_out, int out_size, void* d_ws, size_t ws_size,
                              hipStream_t stream) {
  const float* h   = (const float*)d_in[0];
  const float* x   = (const float*)d_in[1];
  const float* v   = (const float*)d_in[2];
  const int* idx_i = (const int*)d_in[3];
  const int* idx_j = (const int*)d_in[4];
  const float* W_edge_in  = (const float*)d_in[5];
  const float* b_edge_in  = (const float*)d_in[6];
  const float* W_edge_h   = (const float*)d_in[7];
  const float* b_edge_h   = (const float*)d_in[8];
  const float* W_edge_out = (const float*)d_in[9];
  const float* b_edge_out = (const float*)d_in[10];
  const float* W_att      = (const float*)d_in[11];
  const float* b_att      = (const float*)d_in[12];
  const float* W_x_mix    = (const float*)d_in[13];
  const float* W_node1    = (const float*)d_in[14];
  const float* b_node1    = (const float*)d_in[15];
  const float* W_node2    = (const float*)d_in[16];
  const float* b_node2    = (const float*)d_in[17];
  const float* W_post1    = (const float*)d_in[18];
  const float* b_post1    = (const float*)d_in[19];
  const float* W_post2    = (const float*)d_in[20];
  const float* b_post2    = (const float*)d_in[21];
  const float* W_vel1     = (const float*)d_in[22];
  const float* b_vel1     = (const float*)d_in[23];
  const float* W_vel2     = (const float*)d_in[24];
  const float* w_v_mix    = (const float*)d_in[25];

  const int E = in_sizes[3];
  const int N = in_sizes[0] / DA;

  float* ws = (float*)d_ws;
  size_t off = 0;
  float* denom    = ws + off; off += (size_t)N * 4;     // zeroed
  int*   deg      = (int*)(ws + off); off += (size_t)N; // zeroed
  const size_t zeroBytes = off * sizeof(float);
  float* counts   = ws + off; off += (size_t)N;
  int*   rowstart = (int*)(ws + off); off += (size_t)N + 4;
  int*   cursor   = (int*)(ws + off); off += (size_t)N;
  int*   tsum     = (int*)(ws + off); off += (size_t)SCAN_T;
  int*   iperm    = (int*)(ws + off); off += (size_t)E;
  int*   jperm    = (int*)(ws + off); off += (size_t)E;
  float* pE       = ws + off; off += (size_t)E;
  float* expl     = ws + off; off += (size_t)E * 4;
  float* dirb     = ws + off; off += (size_t)E * 3;
  float* hsemR    = ws + off; off += (size_t)N * 64;
  float* comb_sum = ws + off; off += (size_t)N * 96;
  float* dv_sum   = ws + off; off += (size_t)N * 4;
  float* hbfR     = ws + off; off += (size_t)N * 32;
  float* fltR     = ws + off; off += (size_t)E * 16;    // mixE / nh
  float* hebR     = ws + off; off += (size_t)E * 16;

  ushort_t* h_bf = (ushort_t*)hbfR;
  ushort_t* hsem = (ushort_t*)hsemR;
  ushort_t* heb  = (ushort_t*)hebR;
  ushort_t* mixE = (ushort_t*)fltR;
  ushort_t* nh   = (ushort_t*)fltR;

  hipMemsetAsync(d_ws, 0, zeroBytes, stream);

  {
    const int n4 = (N * 64) / 4;
    cast_h<<<(n4 + 255) / 256, 256, 0, stream>>>(h, h_bf, n4);
  }
  deg_count<<<512, 256, 0, stream>>>(idx_i, deg, E);
  {
    const int C = (N + SCAN_T - 1) / SCAN_T;
    deg_tsum<<<SCAN_B, 256, 0, stream>>>(deg, tsum, N, C);
    scan_tsum<<<1, 256, 0, stream>>>(tsum);
    write_csr<<<SCAN_B, 256, 0, stream>>>(deg, tsum, rowstart, cursor, counts, N, C);
  }
  bucket_edges<<<512, 256, 0, stream>>>(idx_i, idx_j, cursor, iperm, jperm, E);
  edge_f12<<<1024, 256, 0, stream>>>(h_bf, x, iperm, jperm,
                                     W_edge_in, b_edge_in, W_edge_h, b_edge_h,
                                     W_edge_out, b_edge_out, W_att, b_att,
                                     dirb, heb, expl, denom, E);
  mix_kernel<<<1024, 256, 0, stream>>>(heb, iperm, expl, denom, W_x_mix,
                                       w_v_mix, mixE, pE, E);
  node_reduce<<<2048, 256, 0, stream>>>(rowstart, heb, mixE, expl, denom,
                                        dirb, pE, hsem, comb_sum, dv_sum, N);
  node_c1_mfma<<<512, 256, 0, stream>>>(
      h_bf, hsem, comb_sum, counts, W_post1, b_post1, W_post2, b_post2,
      W_node1, b_node1, nh, N);
  node_c2_mfma<<<512, 256, 0, stream>>>(
      h, x, v, nh, dv_sum, counts, W_node2, b_node2, W_vel1, b_vel1, W_vel2,
      (float*)d_out, N);
}